// Round 10
// baseline (162.403 us; speedup 1.0000x reference)
//
#include <hip/hip_runtime.h>
#include <hip/hip_bf16.h>
#include <stdint.h>

#define NUM_HEADS 6
#define HEAD_DIM  64
#define EMB       384
#define SEQ       2048
#define NBATCH    8
#define NBH       48        // B*H
#define QKV_COLS  1152
#define ROWS      16384     // B*SEQ
#define L2E       1.44269504f

typedef __attribute__((ext_vector_type(8))) short bf16x8;
typedef __attribute__((ext_vector_type(4))) short bf16x4;
typedef __attribute__((ext_vector_type(4))) float f32x4;
typedef __attribute__((ext_vector_type(4))) unsigned int u32x4;

typedef const __attribute__((address_space(1))) void gas_void;
typedef __attribute__((address_space(3))) void las_void;

static __device__ __forceinline__ short f2bf(float f) {
    __hip_bfloat16 h = __float2bfloat16(f);     // HW RNE
    return __builtin_bit_cast(short, h);
}
static __device__ __forceinline__ uint32_t pk2(float lo, float hi) {
    return (uint32_t)(uint16_t)f2bf(lo) | ((uint32_t)(uint16_t)f2bf(hi) << 16);
}

// ---------- fused prep: xcvt (blocks 0..3071) + wtrans qkv_w (3072..3503) + wtrans proj_w (3504..3647)
__global__ void prep_kernel(const float* __restrict__ x,
                            const float* __restrict__ qkv_w, const float* __restrict__ proj_w,
                            short* __restrict__ Xb, short* __restrict__ qkv_wT, short* __restrict__ proj_wT)
{
    __shared__ float tile[32][33];
    const int id = blockIdx.x, tid = threadIdx.x;
    if (id < 3072) {                       // X f32 -> bf16, 8 elems/thread
        int i = (id * 256 + tid) * 8;
        f32x4 a = *(const f32x4*)&x[i];
        f32x4 b = *(const f32x4*)&x[i + 4];
        bf16x8 o;
        o[0] = f2bf(a[0]); o[1] = f2bf(a[1]); o[2] = f2bf(a[2]); o[3] = f2bf(a[3]);
        o[4] = f2bf(b[0]); o[5] = f2bf(b[1]); o[6] = f2bf(b[2]); o[7] = f2bf(b[3]);
        *(bf16x8*)&Xb[i] = o;
        return;
    }
    const float* in; short* outp; int cols, bx, by;
    if (id < 3504) { in = qkv_w; outp = qkv_wT; cols = QKV_COLS; bx = (id - 3072) % 36; by = (id - 3072) / 36; }
    else           { in = proj_w; outp = proj_wT; cols = EMB;    bx = (id - 3504) % 12; by = (id - 3504) / 12; }
    const int c0 = bx * 32, r0 = by * 32;
    const int xx = tid & 31, yy = tid >> 5;     // 32 x 8
#pragma unroll
    for (int i = 0; i < 32; i += 8)
        tile[yy + i][xx] = in[(size_t)(r0 + yy + i) * cols + c0 + xx];
    __syncthreads();
#pragma unroll
    for (int i = 0; i < 32; i += 8)
        outp[(size_t)(c0 + yy + i) * EMB + r0 + xx] = f2bf(tile[xx][yy + i]);
}

#define BM 128
#define BN 128
#define BK 64

// ---------- QKV GEMM: Xb[16384][384] bf16 @ WT[1152][384] bf16 -> Q(x0.125*log2e),K [B,H,N,D], V^T [B,H,D,N]
__global__ __launch_bounds__(256, 2) void qkv_gemm_kernel(
    const short* __restrict__ Xb, const short* __restrict__ WT,
    const float* __restrict__ bias,
    short* __restrict__ Qb, short* __restrict__ Kb, short* __restrict__ Vt)
{
    __shared__ alignas(16) char smem[2][32768];   // [buf][A 16K | B 16K]; reused as Tt in epilogue
    const int orig = blockIdx.x;
    const int wgid = (orig & 7) * 144 + (orig >> 3);   // XCD-chunked
    const int m0 = (wgid / 9) * BM;
    const int n0 = (wgid % 9) * BN;
    const int tid = threadIdx.x;
    const int lane = tid & 63, wid = tid >> 6;
    const int wm = wid >> 1, wn = wid & 1;
    const int lr = lane & 15, lg = lane >> 4;
    const char* Xc = (const char*)Xb;
    const char* Wc = (const char*)WT;

    const int t_r = wid * 32 + (lane >> 3);
    const int t_cb = ((lane & 7) * 16) ^ (((lane >> 3) & 7) << 4);

#define GSTAGE(buf, k0)                                                                     \
    do {                                                                                    \
        _Pragma("unroll") for (int i = 0; i < 4; ++i)                                       \
            __builtin_amdgcn_global_load_lds(                                               \
                (gas_void*)(Xc + ((size_t)(m0 + t_r + i * 8)) * (EMB * 2) + (k0) * 2 + t_cb), \
                (las_void*)(&smem[buf][wid * 4096 + i * 1024]), 16, 0, 0);                  \
        _Pragma("unroll") for (int i = 0; i < 4; ++i)                                       \
            __builtin_amdgcn_global_load_lds(                                               \
                (gas_void*)(Wc + ((size_t)(n0 + t_r + i * 8)) * (EMB * 2) + (k0) * 2 + t_cb), \
                (las_void*)(&smem[buf][16384 + wid * 4096 + i * 1024]), 16, 0, 0);          \
    } while (0)

    f32x4 acc[4][4] = {};

    GSTAGE(0, 0);
    __syncthreads();
    for (int t = 0; t < EMB / BK; ++t) {
        const int cur = t & 1;
        if (t + 1 < EMB / BK) GSTAGE(cur ^ 1, (t + 1) * BK);
        const char* Ab = smem[cur];
        const char* Bb = smem[cur] + 16384;
        __builtin_amdgcn_s_setprio(1);
#pragma unroll
        for (int kk = 0; kk < 2; ++kk) {
            bf16x8 af[4], bg[4];
#pragma unroll
            for (int mi = 0; mi < 4; ++mi) {
                const int row = wm * 64 + mi * 16 + lr;
                af[mi] = *(const bf16x8*)(Ab + row * 128 + ((kk * 64 + lg * 16) ^ ((row & 7) << 4)));
            }
#pragma unroll
            for (int ni = 0; ni < 4; ++ni) {
                const int row = wn * 64 + ni * 16 + lr;
                bg[ni] = *(const bf16x8*)(Bb + row * 128 + ((kk * 64 + lg * 16) ^ ((row & 7) << 4)));
            }
#pragma unroll
            for (int mi = 0; mi < 4; ++mi)
#pragma unroll
                for (int ni = 0; ni < 4; ++ni)
                    acc[mi][ni] = __builtin_amdgcn_mfma_f32_16x16x32_bf16(af[mi], bg[ni], acc[mi][ni], 0, 0, 0);
        }
        __builtin_amdgcn_s_setprio(0);
        __syncthreads();
    }
#undef GSTAGE

    const int mat = n0 / EMB;
    if (mat != 2) {
#pragma unroll
        for (int ni = 0; ni < 4; ++ni) {
            int col = n0 + wn * 64 + ni * 16 + lr;
            float bv = bias[col];
            int rem = col - mat * EMB;
            int h = rem >> 6, d = rem & 63;
#pragma unroll
            for (int mi = 0; mi < 4; ++mi) {
#pragma unroll
                for (int j = 0; j < 4; ++j) {
                    int row = m0 + wm * 64 + mi * 16 + lg * 4 + j;
                    int b = row >> 11, n = row & 2047;
                    float v = acc[mi][ni][j] + bv;
                    size_t bh = (size_t)(b * NUM_HEADS + h);
                    if (mat == 0) Qb[(bh * SEQ + n) * HEAD_DIM + d] = f2bf(v * (0.125f * L2E));
                    else          Kb[(bh * SEQ + n) * HEAD_DIM + d] = f2bf(v);
                }
            }
        }
    } else {
        // V: transpose tile through LDS -> coalesced bf16x8 stores into V^T [B,H,D,N]
        short (*Tt)[136] = (short (*)[136])&smem[0][0];
#pragma unroll
        for (int ni = 0; ni < 4; ++ni) {
            int col = n0 + wn * 64 + ni * 16 + lr;
            float bv = bias[col];
            int c_loc = wn * 64 + ni * 16 + lr;
#pragma unroll
            for (int mi = 0; mi < 4; ++mi) {
                bf16x4 o4;
#pragma unroll
                for (int j = 0; j < 4; ++j)
                    o4[j] = f2bf(acc[mi][ni][j] + bv);
                *(bf16x4*)&Tt[c_loc][wm * 64 + mi * 16 + lg * 4] = o4;
            }
        }
        __syncthreads();
        const int b = m0 >> 11, nbase = m0 & 2047;
        const int d_loc = tid >> 1;
        const int nn = (tid & 1) * 64;
        const int rem = n0 - 2 * EMB + d_loc;
        const int h = rem >> 6, d = rem & 63;
        short* dst = Vt + ((size_t)(b * NUM_HEADS + h) * HEAD_DIM + d) * SEQ + nbase + nn;
#pragma unroll
        for (int e = 0; e < 8; ++e)
            *(bf16x8*)&dst[e * 8] = *(const bf16x8*)&Tt[d_loc][nn + e * 8];
    }
}

// ---------- flash attention: BARRIER-FREE, 1 wave per block, 64 q-rows per wave.
// Each block privately owns K2+V2 LDS (32 KB -> 5 blocks/CU); staging via global_load_lds,
// synced purely by per-wave s_waitcnt vmcnt(16) -- zero barriers, zero cross-wave coupling.
// Permuted K layout (key pi(r)) keeps P fragments lane-local (no shuffles, no P buffer).
// Max-free softmax (Q pre-scaled to 0.125*log2e); lsum on the matrix pipe via ones-MFMA.
__global__ __launch_bounds__(64, 1) void attn_kernel(
    const short* __restrict__ Qb, const short* __restrict__ Kb,
    const short* __restrict__ Vg, short* __restrict__ AO)
{
    __shared__ alignas(16) char Kl[2][8192];   // [64 rows][128 B], permuted keys, swizzled
    __shared__ alignas(16) char Vl[2][8192];   // [64 d][128 B], swizzled

    // bijective XCD swizzle: 1536 wgs = 8 XCDs x 192 -> 6 heads per XCD (3 MB K+V in 4 MB L2)
    const int orig = blockIdx.x;
    const int wgid = (orig & 7) * 192 + (orig >> 3);
    const int bh = wgid >> 5;          // 48 heads
    const int qb = wgid & 31;          // 32 q-waves of 64 q
    const int lane = threadIdx.x;      // 0..63
    const int lr = lane & 15, lg = lane >> 4;
    const int q0 = qb * 64;
    const short* Qh = Qb + (size_t)bh * SEQ * HEAD_DIM;
    const char*  Khc = (const char*)(Kb + (size_t)bh * SEQ * HEAD_DIM);
    const char*  Vhc = (const char*)(Vg + (size_t)bh * HEAD_DIM * SEQ);

    // stage geometry: inst i covers LDS rows 8i..8i+7; lane writes 16 B at row=8i+(lane>>3),
    // colbyte=(lane&7)*16 swizzled. K source rows permuted by pi for lane-local P fragments.
    const int srow = lane >> 3;                                  // 0..7
    const int scb  = ((lane & 7) * 16) ^ (srow << 4);
    int kpo[8], vpo[8];                                          // per-lane source byte offsets
#pragma unroll
    for (int i = 0; i < 8; ++i) {
        const int r = i * 8 + srow;
        const int key = ((r >> 4) & 1) * 32 + ((r >> 2) & 3) * 8 + ((r >> 5) & 1) * 4 + (r & 3);
        kpo[i] = key * 128 + scb;
        vpo[i] = r * (SEQ * 2) + scb;
    }

#define STAGE(kp, vp, kbase)                                                            \
    do {                                                                                \
        _Pragma("unroll") for (int i = 0; i < 8; ++i)                                   \
            __builtin_amdgcn_global_load_lds(                                           \
                (gas_void*)(Khc + (size_t)(kbase) * 128 + kpo[i]),                      \
                (las_void*)((kp) + i * 1024), 16, 0, 0);                                \
        _Pragma("unroll") for (int i = 0; i < 8; ++i)                                   \
            __builtin_amdgcn_global_load_lds(                                           \
                (gas_void*)(Vhc + (size_t)(kbase) * 2 + vpo[i]),                        \
                (las_void*)((vp) + i * 1024), 16, 0, 0);                                \
    } while (0)

    // Q fragments for 4 chunks of 16 q (held in registers for the whole kernel)
    bf16x8 qf[4][2];
#pragma unroll
    for (int c2 = 0; c2 < 4; ++c2)
#pragma unroll
        for (int kk = 0; kk < 2; ++kk)
            qf[c2][kk] = *(const bf16x8*)&Qh[(size_t)(q0 + c2 * 16 + lr) * HEAD_DIM + kk * 32 + lg * 8];

    bf16x8 ones;
#pragma unroll
    for (int e = 0; e < 8; ++e) ones[e] = (short)0x3F80;   // bf16 1.0

    f32x4 acc[4][4] = {};     // acc[c2][f][j] = O^T[d=f*16+lg*4+j][q=lr (chunk c2)]
    f32x4 accl[4] = {};       // lsum[q=lr] via ones-row MFMA

    char *cK = &Kl[0][0], *nK = &Kl[1][0];
    char *cV = &Vl[0][0], *nV = &Vl[1][0];

    STAGE(cK, cV, 0);                 // 16 loads in flight

    for (int t = 0; t < SEQ / 64; ++t) {
        const int tn = (t + 1 < SEQ / 64 ? t + 1 : SEQ / 64 - 1) * 64;
        STAGE(nK, nV, tn);                                  // 32 outstanding
        asm volatile("s_waitcnt vmcnt(16)" ::: "memory");   // tile t landed (own-wave FIFO)

        // QK(t): S^T = K . Q^T for all 4 q-chunks, sharing each K fragment read
        f32x4 s_[4][4] = {};
        __builtin_amdgcn_s_setprio(1);
#pragma unroll
        for (int c = 0; c < 4; ++c) {
            const int row = c * 16 + lr;
            const int sw = (row & 7) << 4;
            bf16x8 kf0 = *(const bf16x8*)(cK + row * 128 + ((lg * 16) ^ sw));
            bf16x8 kf1 = *(const bf16x8*)(cK + row * 128 + ((64 + lg * 16) ^ sw));
#pragma unroll
            for (int c2 = 0; c2 < 4; ++c2) {
                s_[c2][c] = __builtin_amdgcn_mfma_f32_16x16x32_bf16(kf0, qf[c2][0], s_[c2][c], 0, 0, 0);
                s_[c2][c] = __builtin_amdgcn_mfma_f32_16x16x32_bf16(kf1, qf[c2][1], s_[c2][c], 0, 0, 0);
            }
        }
        __builtin_amdgcn_s_setprio(0);

        // SM(t): max-free exp2 + lane-local pack (permuted K makes P fragments lane-local)
        bf16x8 pb[4][2];
#pragma unroll
        for (int c2 = 0; c2 < 4; ++c2) {
            u32x4 w0, w1;
            w0[0] = pk2(__builtin_amdgcn_exp2f(s_[c2][0][0]), __builtin_amdgcn_exp2f(s_[c2][0][1]));
            w0[1] = pk2(__builtin_amdgcn_exp2f(s_[c2][0][2]), __builtin_amdgcn_exp2f(s_[c2][0][3]));
            w0[2] = pk2(__builtin_amdgcn_exp2f(s_[c2][2][0]), __builtin_amdgcn_exp2f(s_[c2][2][1]));
            w0[3] = pk2(__builtin_amdgcn_exp2f(s_[c2][2][2]), __builtin_amdgcn_exp2f(s_[c2][2][3]));
            w1[0] = pk2(__builtin_amdgcn_exp2f(s_[c2][1][0]), __builtin_amdgcn_exp2f(s_[c2][1][1]));
            w1[1] = pk2(__builtin_amdgcn_exp2f(s_[c2][1][2]), __builtin_amdgcn_exp2f(s_[c2][1][3]));
            w1[2] = pk2(__builtin_amdgcn_exp2f(s_[c2][3][0]), __builtin_amdgcn_exp2f(s_[c2][3][1]));
            w1[3] = pk2(__builtin_amdgcn_exp2f(s_[c2][3][2]), __builtin_amdgcn_exp2f(s_[c2][3][3]));
            pb[c2][0] = __builtin_bit_cast(bf16x8, w0);
            pb[c2][1] = __builtin_bit_cast(bf16x8, w1);
        }

        // PV(t): O^T += V^T . P^T; lsum += ones . P^T (matrix pipe does the row-sum)
        __builtin_amdgcn_s_setprio(1);
#pragma unroll
        for (int f = 0; f < 4; ++f) {
            const int row = f * 16 + lr;
            const int sw = (row & 7) << 4;
            bf16x8 vf0 = *(const bf16x8*)(cV + row * 128 + ((lg * 16) ^ sw));
            bf16x8 vf1 = *(const bf16x8*)(cV + row * 128 + ((64 + lg * 16) ^ sw));
#pragma unroll
            for (int c2 = 0; c2 < 4; ++c2) {
                acc[c2][f] = __builtin_amdgcn_mfma_f32_16x16x32_bf16(vf0, pb[c2][0], acc[c2][f], 0, 0, 0);
                acc[c2][f] = __builtin_amdgcn_mfma_f32_16x16x32_bf16(vf1, pb[c2][1], acc[c2][f], 0, 0, 0);
            }
        }
#pragma unroll
        for (int c2 = 0; c2 < 4; ++c2) {
            accl[c2] = __builtin_amdgcn_mfma_f32_16x16x32_bf16(ones, pb[c2][0], accl[c2], 0, 0, 0);
            accl[c2] = __builtin_amdgcn_mfma_f32_16x16x32_bf16(ones, pb[c2][1], accl[c2], 0, 0, 0);
        }
        __builtin_amdgcn_s_setprio(0);

        char* tk = cK; cK = nK; nK = tk;
        char* tv = cV; cV = nV; nV = tv;
    }
#undef STAGE

    // epilogue: every lane holds lsum for its q (= lr) in accl[c2][0]
    const int b = bh / NUM_HEADS, h = bh - b * NUM_HEADS;
#pragma unroll
    for (int c2 = 0; c2 < 4; ++c2) {
        const float inv = 1.f / accl[c2][0];
        const size_t rowbase = ((size_t)(b * SEQ + q0 + c2 * 16 + lr)) * EMB + h * HEAD_DIM;
#pragma unroll
        for (int f = 0; f < 4; ++f) {
            bf16x4 o4;
#pragma unroll
            for (int j = 0; j < 4; ++j)
                o4[j] = f2bf(acc[c2][f][j] * inv);
            *(bf16x4*)&AO[rowbase + f * 16 + lg * 4] = o4;
        }
    }
}

// ---------- proj GEMM: AO[16384][384] bf16 @ WT[384][384] bf16 + bias -> f32 out
__global__ __launch_bounds__(256, 3) void proj_gemm_kernel(
    const short* __restrict__ Ain, const short* __restrict__ WT,
    const float* __restrict__ bias, float* __restrict__ Out)
{
    __shared__ alignas(16) char smem[2][24576];   // [buf][A 8K | B 16K]
    const int orig = blockIdx.x;
    const int idx = orig >> 3;
    const int m0 = ((orig & 7) * 32 + idx / 3) * 64;
    const int n0 = (idx % 3) * 128;
    const int tid = threadIdx.x;
    const int lane = tid & 63, wid = tid >> 6;
    const int wm = wid >> 1, wn = wid & 1;
    const int lr = lane & 15, lg = lane >> 4;
    const char* Ac = (const char*)Ain;
    const char* Wc = (const char*)WT;

    const int a_r = wid * 16 + (lane >> 3);
    const int b_r = wid * 32 + (lane >> 3);
    const int t_cb = ((lane & 7) * 16) ^ (((lane >> 3) & 7) << 4);

#define PSTAGE(buf, k0)                                                                     \
    do {                                                                                    \
        _Pragma("unroll") for (int i = 0; i < 2; ++i)                                       \
            __builtin_amdgcn_global_load_lds(                                               \
                (gas_void*)(Ac + ((size_t)(m0 + a_r + i * 8)) * (EMB * 2) + (k0) * 2 + t_cb), \
                (las_void*)(&smem[buf][wid * 2048 + i * 1024]), 16, 0, 0);                  \
        _Pragma("unroll") for (int i = 0; i < 4; ++i)                                       \
            __builtin_amdgcn_global_load_lds(                                               \
                (gas_void*)(Wc + ((size_t)(n0 + b_r + i * 8)) * (EMB * 2) + (k0) * 2 + t_cb), \
                (las_void*)(&smem[buf][8192 + wid * 4096 + i * 1024]), 16, 0, 0);           \
    } while (0)

    f32x4 acc[2][4] = {};

    PSTAGE(0, 0);
    __syncthreads();
    for (int t = 0; t < EMB / BK; ++t) {
        const int cur = t & 1;
        if (t + 1 < EMB / BK) PSTAGE(cur ^ 1, (t + 1) * BK);
        const char* Ab = smem[cur];
        const char* Bb = smem[cur] + 8192;
        __builtin_amdgcn_s_setprio(1);
#pragma unroll
        for (int kk = 0; kk < 2; ++kk) {
            bf16x8 af[2], bg[4];
#pragma unroll
            for (int mi = 0; mi < 2; ++mi) {
                const int row = wm * 32 + mi * 16 + lr;
                af[mi] = *(const bf16x8*)(Ab + row * 128 + ((kk * 64 + lg * 16) ^ ((row & 7) << 4)));
            }
#pragma unroll
            for (int ni = 0; ni < 4; ++ni) {
                const int row = wn * 64 + ni * 16 + lr;
                bg[ni] = *(const bf16x8*)(Bb + row * 128 + ((kk * 64 + lg * 16) ^ ((row & 7) << 4)));
            }
#pragma unroll
            for (int mi = 0; mi < 2; ++mi)
#pragma unroll
                for (int ni = 0; ni < 4; ++ni)
                    acc[mi][ni] = __builtin_amdgcn_mfma_f32_16x16x32_bf16(af[mi], bg[ni], acc[mi][ni], 0, 0, 0);
        }
        __builtin_amdgcn_s_setprio(0);
        __syncthreads();
    }
#undef PSTAGE

#pragma unroll
    for (int ni = 0; ni < 4; ++ni) {
        int col = n0 + wn * 64 + ni * 16 + lr;
        float bv = bias[col];
#pragma unroll
        for (int mi = 0; mi < 2; ++mi)
#pragma unroll
            for (int j = 0; j < 4; ++j) {
                int row = m0 + wm * 32 + mi * 16 + lg * 4 + j;
                Out[(size_t)row * EMB + col] = acc[mi][ni][j] + bv;
            }
    }
}

extern "C" void kernel_launch(void* const* d_in, const int* in_sizes, int n_in,
                              void* d_out, int out_size, void* d_ws, size_t ws_size,
                              hipStream_t stream) {
    const float* x      = (const float*)d_in[0];
    const float* qkv_w  = (const float*)d_in[1];   // [384][1152]
    const float* qkv_b  = (const float*)d_in[2];   // [1152]
    const float* proj_w = (const float*)d_in[3];   // [384][384]
    const float* proj_b = (const float*)d_in[4];   // [384]
    float* out = (float*)d_out;

    // workspace layout (bytes); Xb shares the AO slot (Xb consumed before AO written)
    char* ws = (char*)d_ws;
    short* qkv_wT  = (short*)(ws);               // [1152][384] bf16
    short* proj_wT = (short*)(ws + 884736);      // [384][384]  bf16
    short* Qb      = (short*)(ws + 1179648);     // [B,H,N,D]   bf16 (pre-scaled 0.125*log2e)
    short* Kb      = (short*)(ws + 13762560);    // [B,H,N,D]   bf16
    short* Vt      = (short*)(ws + 26345472);    // [B,H,D,N]   bf16
    short* AOXb    = (short*)(ws + 38928384);    // [B,N,C] bf16: Xb then AO

    prep_kernel<<<dim3(3648), 256, 0, stream>>>(x, qkv_w, proj_w, AOXb, qkv_wT, proj_wT);
    qkv_gemm_kernel<<<dim3(ROWS / BM * (QKV_COLS / BN)), 256, 0, stream>>>(AOXb, qkv_wT, qkv_b, Qb, Kb, Vt);
    attn_kernel<<<dim3(NBH * (SEQ / 64)), 64, 0, stream>>>(Qb, Kb, Vt, AOXb);
    proj_gemm_kernel<<<dim3(ROWS / 64 * (EMB / 128)), 256, 0, stream>>>(AOXb, proj_wT, proj_b, out);
}

// Round 11
// 127.095 us; speedup vs baseline: 1.2778x; 1.2778x over previous
//
#include <hip/hip_runtime.h>
#include <hip/hip_bf16.h>
#include <stdint.h>

#define NUM_HEADS 6
#define HEAD_DIM  64
#define EMB       384
#define SEQ       2048
#define NBATCH    8
#define NBH       48        // B*H
#define QKV_COLS  1152
#define ROWS      16384     // B*SEQ
#define L2E       1.44269504f

typedef __attribute__((ext_vector_type(8))) short bf16x8;
typedef __attribute__((ext_vector_type(4))) short bf16x4;
typedef __attribute__((ext_vector_type(4))) float f32x4;
typedef __attribute__((ext_vector_type(4))) unsigned int u32x4;

typedef const __attribute__((address_space(1))) void gas_void;
typedef __attribute__((address_space(3))) void las_void;

static __device__ __forceinline__ short f2bf(float f) {
    __hip_bfloat16 h = __float2bfloat16(f);     // HW RNE
    return __builtin_bit_cast(short, h);
}
static __device__ __forceinline__ uint32_t pk2(float lo, float hi) {
    return (uint32_t)(uint16_t)f2bf(lo) | ((uint32_t)(uint16_t)f2bf(hi) << 16);
}

// ---------- prep: weight transposes only (X conversion fused into qkv_gemm)
// blocks 0..431: qkv_w [384][1152] -> qkv_wT [1152][384]; 432..575: proj_w -> proj_wT
__global__ void prep_kernel(const float* __restrict__ qkv_w, const float* __restrict__ proj_w,
                            short* __restrict__ qkv_wT, short* __restrict__ proj_wT)
{
    __shared__ float tile[32][33];
    const int id = blockIdx.x, tid = threadIdx.x;
    const float* in; short* outp; int cols, bx, by;
    if (id < 432) { in = qkv_w; outp = qkv_wT; cols = QKV_COLS; bx = id % 36; by = id / 36; }
    else          { in = proj_w; outp = proj_wT; cols = EMB;    bx = (id - 432) % 12; by = (id - 432) / 12; }
    const int c0 = bx * 32, r0 = by * 32;
    const int xx = tid & 31, yy = tid >> 5;     // 32 x 8
#pragma unroll
    for (int i = 0; i < 32; i += 8)
        tile[yy + i][xx] = in[(size_t)(r0 + yy + i) * cols + c0 + xx];
    __syncthreads();
#pragma unroll
    for (int i = 0; i < 32; i += 8)
        outp[(size_t)(c0 + yy + i) * EMB + r0 + xx] = f2bf(tile[xx][yy + i]);
}

#define BM 128
#define BN 128
#define BK 64

// ---------- QKV GEMM: X[16384][384] f32 @ WT[1152][384] bf16 -> Q(x0.125*log2e),K [B,H,N,D], V^T [B,H,D,N]
// A staged from f32 X via reg-load + cvt + swizzled ds_write (T14 split: load early, write late);
// B staged via global_load_lds with pre-swizzled source. LDS fragment layout identical for both.
__global__ __launch_bounds__(256, 2) void qkv_gemm_kernel(
    const float* __restrict__ X, const short* __restrict__ WT,
    const float* __restrict__ bias,
    short* __restrict__ Qb, short* __restrict__ Kb, short* __restrict__ Vt)
{
    __shared__ alignas(16) char smem[2][32768];   // [buf][A 16K | B 16K]; reused as Tt in epilogue
    const int orig = blockIdx.x;
    const int wgid = (orig & 7) * 144 + (orig >> 3);   // XCD-chunked
    const int m0 = (wgid / 9) * BM;
    const int n0 = (wgid % 9) * BN;
    const int tid = threadIdx.x;
    const int lane = tid & 63, wid = tid >> 6;
    const int wm = wid >> 1, wn = wid & 1;
    const int lr = lane & 15, lg = lane >> 4;
    const char* Wc = (const char*)WT;

    // A reg-stage geometry: thread covers row=tid>>1 (0..127), 32 f32 at col half*32
    const int a_row = tid >> 1;
    const int a_half = tid & 1;
    const float* Arow = X + (size_t)(m0 + a_row) * EMB + a_half * 32;
    const int a_swz = (a_row & 7) << 4;

    // B gload geometry
    const int t_r = wid * 32 + (lane >> 3);
    const int t_cb = ((lane & 7) * 16) ^ (((lane >> 3) & 7) << 4);

#define BSTAGE(buf, k0)                                                                     \
    do {                                                                                    \
        _Pragma("unroll") for (int i = 0; i < 4; ++i)                                       \
            __builtin_amdgcn_global_load_lds(                                               \
                (gas_void*)(Wc + ((size_t)(n0 + t_r + i * 8)) * (EMB * 2) + (k0) * 2 + t_cb), \
                (las_void*)(&smem[buf][16384 + wid * 4096 + i * 1024]), 16, 0, 0);          \
    } while (0)

#define ALOAD(R, k0)                                                                        \
    do {                                                                                    \
        _Pragma("unroll") for (int i = 0; i < 8; ++i)                                       \
            R[i] = *(const f32x4*)(Arow + (k0) + i * 4);                                    \
    } while (0)

#define AWRITE(R, buf)                                                                      \
    do {                                                                                    \
        _Pragma("unroll") for (int j = 0; j < 4; ++j) {                                     \
            bf16x8 o_;                                                                      \
            o_[0] = f2bf(R[2*j][0]); o_[1] = f2bf(R[2*j][1]);                               \
            o_[2] = f2bf(R[2*j][2]); o_[3] = f2bf(R[2*j][3]);                               \
            o_[4] = f2bf(R[2*j+1][0]); o_[5] = f2bf(R[2*j+1][1]);                           \
            o_[6] = f2bf(R[2*j+1][2]); o_[7] = f2bf(R[2*j+1][3]);                           \
            *(bf16x8*)&smem[buf][a_row * 128 + ((a_half * 64 + j * 16) ^ a_swz)] = o_;      \
        }                                                                                   \
    } while (0)

    f32x4 acc[4][4] = {};
    f32x4 ar[8];

    ALOAD(ar, 0);
    BSTAGE(0, 0);
    AWRITE(ar, 0);
    __syncthreads();
    for (int t = 0; t < EMB / BK; ++t) {
        const int cur = t & 1;
        if (t + 1 < EMB / BK) { ALOAD(ar, (t + 1) * BK); BSTAGE(cur ^ 1, (t + 1) * BK); }
        const char* Ab = smem[cur];
        const char* Bb = smem[cur] + 16384;
        __builtin_amdgcn_s_setprio(1);
#pragma unroll
        for (int kk = 0; kk < 2; ++kk) {
            bf16x8 af[4], bg[4];
#pragma unroll
            for (int mi = 0; mi < 4; ++mi) {
                const int row = wm * 64 + mi * 16 + lr;
                af[mi] = *(const bf16x8*)(Ab + row * 128 + ((kk * 64 + lg * 16) ^ ((row & 7) << 4)));
            }
#pragma unroll
            for (int ni = 0; ni < 4; ++ni) {
                const int row = wn * 64 + ni * 16 + lr;
                bg[ni] = *(const bf16x8*)(Bb + row * 128 + ((kk * 64 + lg * 16) ^ ((row & 7) << 4)));
            }
#pragma unroll
            for (int mi = 0; mi < 4; ++mi)
#pragma unroll
                for (int ni = 0; ni < 4; ++ni)
                    acc[mi][ni] = __builtin_amdgcn_mfma_f32_16x16x32_bf16(af[mi], bg[ni], acc[mi][ni], 0, 0, 0);
        }
        __builtin_amdgcn_s_setprio(0);
        if (t + 1 < EMB / BK) AWRITE(ar, cur ^ 1);
        __syncthreads();
    }
#undef BSTAGE
#undef ALOAD
#undef AWRITE

    const int mat = n0 / EMB;
    if (mat != 2) {
#pragma unroll
        for (int ni = 0; ni < 4; ++ni) {
            int col = n0 + wn * 64 + ni * 16 + lr;
            float bv = bias[col];
            int rem = col - mat * EMB;
            int h = rem >> 6, d = rem & 63;
#pragma unroll
            for (int mi = 0; mi < 4; ++mi) {
#pragma unroll
                for (int j = 0; j < 4; ++j) {
                    int row = m0 + wm * 64 + mi * 16 + lg * 4 + j;
                    int b = row >> 11, n = row & 2047;
                    float v = acc[mi][ni][j] + bv;
                    size_t bh = (size_t)(b * NUM_HEADS + h);
                    if (mat == 0) Qb[(bh * SEQ + n) * HEAD_DIM + d] = f2bf(v * (0.125f * L2E));
                    else          Kb[(bh * SEQ + n) * HEAD_DIM + d] = f2bf(v);
                }
            }
        }
    } else {
        // V: transpose tile through LDS -> coalesced bf16x8 stores into V^T [B,H,D,N]
        short (*Tt)[136] = (short (*)[136])&smem[0][0];
#pragma unroll
        for (int ni = 0; ni < 4; ++ni) {
            int col = n0 + wn * 64 + ni * 16 + lr;
            float bv = bias[col];
            int c_loc = wn * 64 + ni * 16 + lr;
#pragma unroll
            for (int mi = 0; mi < 4; ++mi) {
                bf16x4 o4;
#pragma unroll
                for (int j = 0; j < 4; ++j)
                    o4[j] = f2bf(acc[mi][ni][j] + bv);
                *(bf16x4*)&Tt[c_loc][wm * 64 + mi * 16 + lg * 4] = o4;
            }
        }
        __syncthreads();
        const int b = m0 >> 11, nbase = m0 & 2047;
        const int d_loc = tid >> 1;
        const int nn = (tid & 1) * 64;
        const int rem = n0 - 2 * EMB + d_loc;
        const int h = rem >> 6, d = rem & 63;
        short* dst = Vt + ((size_t)(b * NUM_HEADS + h) * HEAD_DIM + d) * SEQ + nbase + nn;
#pragma unroll
        for (int e = 0; e < 8; ++e)
            *(bf16x8*)&dst[e * 8] = *(const bf16x8*)&Tt[d_loc][nn + e * 8];
    }
}

// ---------- flash attention (round-8 version, verbatim): counted-vmcnt pipeline,
// strict distance-2, PERMUTED K layout -> lane-local P fragments, max-free softmax,
// lsum on the matrix pipe via ones-MFMA. 48KB LDS -> 3 blocks/CU.
__global__ __launch_bounds__(256, 3) void attn_kernel(
    const short* __restrict__ Qb, const short* __restrict__ Kb,
    const short* __restrict__ Vg, short* __restrict__ AO)
{
    __shared__ alignas(16) char Kl[3][8192];   // [64 rows][128 B], permuted keys, swizzled
    __shared__ alignas(16) char Vl[3][8192];   // [64 d][128 B], swizzled

    // bijective XCD swizzle: 768 wgs = 8 XCDs x 96 -> 6 heads per XCD (3 MB K+V in 4 MB L2)
    const int orig = blockIdx.x;
    const int wgid = (orig & 7) * 96 + (orig >> 3);
    const int bh = wgid >> 4;
    const int qb = wgid & 15;
    const int tid = threadIdx.x, lane = tid & 63, wid = tid >> 6;
    const int lr = lane & 15, lg = lane >> 4;
    const int q0 = qb * 128 + wid * 32;
    const short* Qh = Qb + (size_t)bh * SEQ * HEAD_DIM;
    const char*  Khc = (const char*)(Kb + (size_t)bh * SEQ * HEAD_DIM);
    const char*  Vhc = (const char*)(Vg + (size_t)bh * HEAD_DIM * SEQ);

    const int s_r0 = wid * 16 + (lane >> 3);          // LDS row for stage inst 0
    const int s_cb0 = ((lane & 7) * 16) ^ ((s_r0 & 7) << 4);
    const int s_r1 = s_r0 + 8;                        // LDS row for stage inst 1
    const int s_cb1 = ((lane & 7) * 16) ^ ((s_r1 & 7) << 4);
    // permuted K source rows: key = pi(lds_row)
    const int p_r0 = ((s_r0 >> 4) & 1) * 32 + ((s_r0 >> 2) & 3) * 8 + ((s_r0 >> 5) & 1) * 4 + (s_r0 & 3);
    const int p_r1 = ((s_r1 >> 4) & 1) * 32 + ((s_r1 >> 2) & 3) * 8 + ((s_r1 >> 5) & 1) * 4 + (s_r1 & 3);

#define STAGE(kp, vp, kbase)                                                            \
    do {                                                                                \
        __builtin_amdgcn_global_load_lds(                                               \
            (gas_void*)(Khc + ((size_t)(kbase) + p_r0) * 128 + s_cb0),                  \
            (las_void*)((kp) + wid * 2048), 16, 0, 0);                                  \
        __builtin_amdgcn_global_load_lds(                                               \
            (gas_void*)(Khc + ((size_t)(kbase) + p_r1) * 128 + s_cb1),                  \
            (las_void*)((kp) + wid * 2048 + 1024), 16, 0, 0);                           \
        __builtin_amdgcn_global_load_lds(                                               \
            (gas_void*)(Vhc + (size_t)s_r0 * (SEQ * 2) + (size_t)(kbase) * 2 + s_cb0),  \
            (las_void*)((vp) + wid * 2048), 16, 0, 0);                                  \
        __builtin_amdgcn_global_load_lds(                                               \
            (gas_void*)(Vhc + (size_t)s_r1 * (SEQ * 2) + (size_t)(kbase) * 2 + s_cb1),  \
            (las_void*)((vp) + wid * 2048 + 1024), 16, 0, 0);                           \
    } while (0)

    bf16x8 qf[2][2];
#pragma unroll
    for (int c2 = 0; c2 < 2; ++c2)
#pragma unroll
        for (int kk = 0; kk < 2; ++kk)
            qf[c2][kk] = *(const bf16x8*)&Qh[(size_t)(q0 + c2 * 16 + lr) * HEAD_DIM + kk * 32 + lg * 8];

    bf16x8 ones;
#pragma unroll
    for (int e = 0; e < 8; ++e) ones[e] = (short)0x3F80;   // bf16 1.0

    f32x4 acc[2][4] = {};     // acc[c2][f][j] = O^T[d=f*16+lg*4+j][q=lr (chunk c2)]
    f32x4 accl[2] = {};       // lsum[q=lr] via ones-row MFMA

    char *k0p = &Kl[0][0], *k1p = &Kl[1][0], *k2p = &Kl[2][0];
    char *v0p = &Vl[0][0], *v1p = &Vl[1][0], *v2p = &Vl[2][0];

    // prologue: stage tiles 0,1; own tile-0 loads complete BEFORE the first barrier
    STAGE(k0p, v0p, 0);
    STAGE(k1p, v1p, 64);
    asm volatile("s_waitcnt vmcnt(4)" ::: "memory");

    for (int t = 0; t < SEQ / 64; ++t) {
        __builtin_amdgcn_s_barrier();             // all waves done reading tile t-1; tile t landed
        const int tn = (t + 2 < SEQ / 64 ? t + 2 : SEQ / 64 - 1) * 64;
        STAGE(k2p, v2p, tn);                      // overwrites tile t-1 slots (post-barrier)
        asm volatile("s_waitcnt vmcnt(4)" ::: "memory");   // own tiles <= t+1 landed

        // QK(t): S^T = K . Q^T for both q-chunks, sharing each K fragment read
        f32x4 s_[2][4] = {};
        __builtin_amdgcn_s_setprio(1);
#pragma unroll
        for (int c = 0; c < 4; ++c) {
            const int row = c * 16 + lr;
            const int sw = (row & 7) << 4;
            bf16x8 kf0 = *(const bf16x8*)(k0p + row * 128 + ((lg * 16) ^ sw));
            bf16x8 kf1 = *(const bf16x8*)(k0p + row * 128 + ((64 + lg * 16) ^ sw));
            s_[0][c] = __builtin_amdgcn_mfma_f32_16x16x32_bf16(kf0, qf[0][0], s_[0][c], 0, 0, 0);
            s_[0][c] = __builtin_amdgcn_mfma_f32_16x16x32_bf16(kf1, qf[0][1], s_[0][c], 0, 0, 0);
            s_[1][c] = __builtin_amdgcn_mfma_f32_16x16x32_bf16(kf0, qf[1][0], s_[1][c], 0, 0, 0);
            s_[1][c] = __builtin_amdgcn_mfma_f32_16x16x32_bf16(kf1, qf[1][1], s_[1][c], 0, 0, 0);
        }
        __builtin_amdgcn_s_setprio(0);

        // SM(t): max-free exp2 + lane-local pack (permuted K makes P fragments lane-local)
        bf16x8 pb[2][2];
#pragma unroll
        for (int c2 = 0; c2 < 2; ++c2) {
            u32x4 w0, w1;
            w0[0] = pk2(__builtin_amdgcn_exp2f(s_[c2][0][0]), __builtin_amdgcn_exp2f(s_[c2][0][1]));
            w0[1] = pk2(__builtin_amdgcn_exp2f(s_[c2][0][2]), __builtin_amdgcn_exp2f(s_[c2][0][3]));
            w0[2] = pk2(__builtin_amdgcn_exp2f(s_[c2][2][0]), __builtin_amdgcn_exp2f(s_[c2][2][1]));
            w0[3] = pk2(__builtin_amdgcn_exp2f(s_[c2][2][2]), __builtin_amdgcn_exp2f(s_[c2][2][3]));
            w1[0] = pk2(__builtin_amdgcn_exp2f(s_[c2][1][0]), __builtin_amdgcn_exp2f(s_[c2][1][1]));
            w1[1] = pk2(__builtin_amdgcn_exp2f(s_[c2][1][2]), __builtin_amdgcn_exp2f(s_[c2][1][3]));
            w1[2] = pk2(__builtin_amdgcn_exp2f(s_[c2][3][0]), __builtin_amdgcn_exp2f(s_[c2][3][1]));
            w1[3] = pk2(__builtin_amdgcn_exp2f(s_[c2][3][2]), __builtin_amdgcn_exp2f(s_[c2][3][3]));
            pb[c2][0] = __builtin_bit_cast(bf16x8, w0);
            pb[c2][1] = __builtin_bit_cast(bf16x8, w1);
        }

        // PV(t): O^T += V^T . P^T; lsum += ones . P^T (matrix pipe does the row-sum)
        __builtin_amdgcn_s_setprio(1);
#pragma unroll
        for (int f = 0; f < 4; ++f) {
            const int row = f * 16 + lr;
            const int sw = (row & 7) << 4;
            bf16x8 vf0 = *(const bf16x8*)(v0p + row * 128 + ((lg * 16) ^ sw));
            bf16x8 vf1 = *(const bf16x8*)(v0p + row * 128 + ((64 + lg * 16) ^ sw));
            acc[0][f] = __builtin_amdgcn_mfma_f32_16x16x32_bf16(vf0, pb[0][0], acc[0][f], 0, 0, 0);
            acc[0][f] = __builtin_amdgcn_mfma_f32_16x16x32_bf16(vf1, pb[0][1], acc[0][f], 0, 0, 0);
            acc[1][f] = __builtin_amdgcn_mfma_f32_16x16x32_bf16(vf0, pb[1][0], acc[1][f], 0, 0, 0);
            acc[1][f] = __builtin_amdgcn_mfma_f32_16x16x32_bf16(vf1, pb[1][1], acc[1][f], 0, 0, 0);
        }
        accl[0] = __builtin_amdgcn_mfma_f32_16x16x32_bf16(ones, pb[0][0], accl[0], 0, 0, 0);
        accl[0] = __builtin_amdgcn_mfma_f32_16x16x32_bf16(ones, pb[0][1], accl[0], 0, 0, 0);
        accl[1] = __builtin_amdgcn_mfma_f32_16x16x32_bf16(ones, pb[1][0], accl[1], 0, 0, 0);
        accl[1] = __builtin_amdgcn_mfma_f32_16x16x32_bf16(ones, pb[1][1], accl[1], 0, 0, 0);
        __builtin_amdgcn_s_setprio(0);

        // rotate buffers: read slot <- next, next <- staged, staged <- retired
        char* kt_ = k0p; k0p = k1p; k1p = k2p; k2p = kt_;
        char* vt_ = v0p; v0p = v1p; v1p = v2p; v2p = vt_;
    }
#undef STAGE

    // epilogue: every lane holds lsum for its q (= lr) in accl
    const int b = bh / NUM_HEADS, h = bh - b * NUM_HEADS;
#pragma unroll
    for (int c2 = 0; c2 < 2; ++c2) {
        const float inv = 1.f / accl[c2][0];
        const size_t rowbase = ((size_t)(b * SEQ + q0 + c2 * 16 + lr)) * EMB + h * HEAD_DIM;
#pragma unroll
        for (int f = 0; f < 4; ++f) {
            bf16x4 o4;
#pragma unroll
            for (int j = 0; j < 4; ++j)
                o4[j] = f2bf(acc[c2][f][j] * inv);
            *(bf16x4*)&AO[rowbase + f * 16 + lg * 4] = o4;
        }
    }
}

// ---------- proj GEMM: AO[16384][384] bf16 @ WT[384][384] bf16 + bias -> f32 out
__global__ __launch_bounds__(256, 3) void proj_gemm_kernel(
    const short* __restrict__ Ain, const short* __restrict__ WT,
    const float* __restrict__ bias, float* __restrict__ Out)
{
    __shared__ alignas(16) char smem[2][24576];   // [buf][A 8K | B 16K]
    const int orig = blockIdx.x;
    const int idx = orig >> 3;
    const int m0 = ((orig & 7) * 32 + idx / 3) * 64;
    const int n0 = (idx % 3) * 128;
    const int tid = threadIdx.x;
    const int lane = tid & 63, wid = tid >> 6;
    const int wm = wid >> 1, wn = wid & 1;
    const int lr = lane & 15, lg = lane >> 4;
    const char* Ac = (const char*)Ain;
    const char* Wc = (const char*)WT;

    const int a_r = wid * 16 + (lane >> 3);
    const int b_r = wid * 32 + (lane >> 3);
    const int t_cb = ((lane & 7) * 16) ^ (((lane >> 3) & 7) << 4);

#define PSTAGE(buf, k0)                                                                     \
    do {                                                                                    \
        _Pragma("unroll") for (int i = 0; i < 2; ++i)                                       \
            __builtin_amdgcn_global_load_lds(                                               \
                (gas_void*)(Ac + ((size_t)(m0 + a_r + i * 8)) * (EMB * 2) + (k0) * 2 + t_cb), \
                (las_void*)(&smem[buf][wid * 2048 + i * 1024]), 16, 0, 0);                  \
        _Pragma("unroll") for (int i = 0; i < 4; ++i)                                       \
            __builtin_amdgcn_global_load_lds(                                               \
                (gas_void*)(Wc + ((size_t)(n0 + b_r + i * 8)) * (EMB * 2) + (k0) * 2 + t_cb), \
                (las_void*)(&smem[buf][8192 + wid * 4096 + i * 1024]), 16, 0, 0);           \
    } while (0)

    f32x4 acc[2][4] = {};

    PSTAGE(0, 0);
    __syncthreads();
    for (int t = 0; t < EMB / BK; ++t) {
        const int cur = t & 1;
        if (t + 1 < EMB / BK) PSTAGE(cur ^ 1, (t + 1) * BK);
        const char* Ab = smem[cur];
        const char* Bb = smem[cur] + 8192;
        __builtin_amdgcn_s_setprio(1);
#pragma unroll
        for (int kk = 0; kk < 2; ++kk) {
            bf16x8 af[2], bg[4];
#pragma unroll
            for (int mi = 0; mi < 2; ++mi) {
                const int row = wm * 32 + mi * 16 + lr;
                af[mi] = *(const bf16x8*)(Ab + row * 128 + ((kk * 64 + lg * 16) ^ ((row & 7) << 4)));
            }
#pragma unroll
            for (int ni = 0; ni < 4; ++ni) {
                const int row = wn * 64 + ni * 16 + lr;
                bg[ni] = *(const bf16x8*)(Bb + row * 128 + ((kk * 64 + lg * 16) ^ ((row & 7) << 4)));
            }
#pragma unroll
            for (int mi = 0; mi < 2; ++mi)
#pragma unroll
                for (int ni = 0; ni < 4; ++ni)
                    acc[mi][ni] = __builtin_amdgcn_mfma_f32_16x16x32_bf16(af[mi], bg[ni], acc[mi][ni], 0, 0, 0);
        }
        __builtin_amdgcn_s_setprio(0);
        __syncthreads();
    }
#undef PSTAGE

#pragma unroll
    for (int ni = 0; ni < 4; ++ni) {
        int col = n0 + wn * 64 + ni * 16 + lr;
        float bv = bias[col];
#pragma unroll
        for (int mi = 0; mi < 2; ++mi)
#pragma unroll
            for (int j = 0; j < 4; ++j) {
                int row = m0 + wm * 32 + mi * 16 + lg * 4 + j;
                Out[(size_t)row * EMB + col] = acc[mi][ni][j] + bv;
            }
    }
}

extern "C" void kernel_launch(void* const* d_in, const int* in_sizes, int n_in,
                              void* d_out, int out_size, void* d_ws, size_t ws_size,
                              hipStream_t stream) {
    const float* x      = (const float*)d_in[0];
    const float* qkv_w  = (const float*)d_in[1];   // [384][1152]
    const float* qkv_b  = (const float*)d_in[2];   // [1152]
    const float* proj_w = (const float*)d_in[3];   // [384][384]
    const float* proj_b = (const float*)d_in[4];   // [384]
    float* out = (float*)d_out;

    // workspace layout (bytes)
    char* ws = (char*)d_ws;
    short* qkv_wT  = (short*)(ws);               // [1152][384] bf16
    short* proj_wT = (short*)(ws + 884736);      // [384][384]  bf16
    short* Qb      = (short*)(ws + 1179648);     // [B,H,N,D]   bf16 (pre-scaled 0.125*log2e)
    short* Kb      = (short*)(ws + 13762560);    // [B,H,N,D]   bf16
    short* Vt      = (short*)(ws + 26345472);    // [B,H,D,N]   bf16
    short* AO      = (short*)(ws + 38928384);    // [B,N,C]     bf16

    prep_kernel<<<dim3(576), 256, 0, stream>>>(qkv_w, proj_w, qkv_wT, proj_wT);
    qkv_gemm_kernel<<<dim3(ROWS / BM * (QKV_COLS / BN)), 256, 0, stream>>>(x, qkv_wT, qkv_b, Qb, Kb, Vt);
    attn_kernel<<<dim3(NBH * (SEQ / 128)), 256, 0, stream>>>(Qb, Kb, Vt, AO);
    proj_gemm_kernel<<<dim3(ROWS / 64 * (EMB / 128)), 256, 0, stream>>>(AO, proj_wT, proj_b, out);
}

// Round 12
// 116.337 us; speedup vs baseline: 1.3960x; 1.0925x over previous
//
#include <hip/hip_runtime.h>
#include <hip/hip_bf16.h>
#include <stdint.h>

#define NUM_HEADS 6
#define HEAD_DIM  64
#define EMB       384
#define SEQ       2048
#define NBATCH    8
#define NBH       48        // B*H
#define QKV_COLS  1152
#define ROWS      16384     // B*SEQ
#define L2E       1.44269504f

typedef __attribute__((ext_vector_type(8))) short bf16x8;
typedef __attribute__((ext_vector_type(4))) short bf16x4;
typedef __attribute__((ext_vector_type(4))) float f32x4;
typedef __attribute__((ext_vector_type(4))) unsigned int u32x4;

typedef const __attribute__((address_space(1))) void gas_void;
typedef __attribute__((address_space(3))) void las_void;

static __device__ __forceinline__ short f2bf(float f) {
    __hip_bfloat16 h = __float2bfloat16(f);     // HW RNE
    return __builtin_bit_cast(short, h);
}
static __device__ __forceinline__ uint32_t pk2(float lo, float hi) {
    return (uint32_t)(uint16_t)f2bf(lo) | ((uint32_t)(uint16_t)f2bf(hi) << 16);
}

// ---------- fused prep: xcvt (blocks 0..3071) + wtrans qkv_w (3072..3503) + wtrans proj_w (3504..3647)
__global__ void prep_kernel(const float* __restrict__ x,
                            const float* __restrict__ qkv_w, const float* __restrict__ proj_w,
                            short* __restrict__ Xb, short* __restrict__ qkv_wT, short* __restrict__ proj_wT)
{
    __shared__ float tile[32][33];
    const int id = blockIdx.x, tid = threadIdx.x;
    if (id < 3072) {                       // X f32 -> bf16, 8 elems/thread
        int i = (id * 256 + tid) * 8;
        f32x4 a = *(const f32x4*)&x[i];
        f32x4 b = *(const f32x4*)&x[i + 4];
        bf16x8 o;
        o[0] = f2bf(a[0]); o[1] = f2bf(a[1]); o[2] = f2bf(a[2]); o[3] = f2bf(a[3]);
        o[4] = f2bf(b[0]); o[5] = f2bf(b[1]); o[6] = f2bf(b[2]); o[7] = f2bf(b[3]);
        *(bf16x8*)&Xb[i] = o;
        return;
    }
    const float* in; short* outp; int cols, bx, by;
    if (id < 3504) { in = qkv_w; outp = qkv_wT; cols = QKV_COLS; bx = (id - 3072) % 36; by = (id - 3072) / 36; }
    else           { in = proj_w; outp = proj_wT; cols = EMB;    bx = (id - 3504) % 12; by = (id - 3504) / 12; }
    const int c0 = bx * 32, r0 = by * 32;
    const int xx = tid & 31, yy = tid >> 5;     // 32 x 8
#pragma unroll
    for (int i = 0; i < 32; i += 8)
        tile[yy + i][xx] = in[(size_t)(r0 + yy + i) * cols + c0 + xx];
    __syncthreads();
#pragma unroll
    for (int i = 0; i < 32; i += 8)
        outp[(size_t)(c0 + yy + i) * EMB + r0 + xx] = f2bf(tile[xx][yy + i]);
}

#define BM 128
#define BN 128
#define BK 64

// ---------- QKV GEMM: Xb[16384][384] bf16 @ WT[1152][384] bf16 -> Q(x0.125*log2e),K [B,H,N,D], V^T [B,H,D,N]
// 512 threads (8 waves, 2x4 wave grid) with the SAME 64KB LDS and 128x128 tile:
// 2 blocks/CU now carry 16 waves/CU (was 8) to hide the staging drain before barriers.
__global__ __launch_bounds__(512, 4) void qkv_gemm_kernel(
    const short* __restrict__ Xb, const short* __restrict__ WT,
    const float* __restrict__ bias,
    short* __restrict__ Qb, short* __restrict__ Kb, short* __restrict__ Vt)
{
    __shared__ alignas(16) char smem[2][32768];   // [buf][A 16K | B 16K]; reused as Tt in epilogue
    const int orig = blockIdx.x;
    const int wgid = (orig & 7) * 144 + (orig >> 3);   // XCD-chunked
    const int m0 = (wgid / 9) * BM;
    const int n0 = (wgid % 9) * BN;
    const int tid = threadIdx.x;
    const int lane = tid & 63, wid = tid >> 6;    // 0..7
    const int wm = wid >> 2, wn = wid & 3;        // 2 x 4 wave grid
    const int lr = lane & 15, lg = lane >> 4;
    const char* Xc = (const char*)Xb;
    const char* Wc = (const char*)WT;

    const int t_r = wid * 16 + (lane >> 3);       // rows wid*16 + i*8 + (lane>>3)
    const int t_cb = ((lane & 7) * 16) ^ (((lane >> 3) & 7) << 4);

#define GSTAGE(buf, k0)                                                                     \
    do {                                                                                    \
        _Pragma("unroll") for (int i = 0; i < 2; ++i)                                       \
            __builtin_amdgcn_global_load_lds(                                               \
                (gas_void*)(Xc + ((size_t)(m0 + t_r + i * 8)) * (EMB * 2) + (k0) * 2 + t_cb), \
                (las_void*)(&smem[buf][wid * 2048 + i * 1024]), 16, 0, 0);                  \
        _Pragma("unroll") for (int i = 0; i < 2; ++i)                                       \
            __builtin_amdgcn_global_load_lds(                                               \
                (gas_void*)(Wc + ((size_t)(n0 + t_r + i * 8)) * (EMB * 2) + (k0) * 2 + t_cb), \
                (las_void*)(&smem[buf][16384 + wid * 2048 + i * 1024]), 16, 0, 0);          \
    } while (0)

    f32x4 acc[4][2] = {};

    GSTAGE(0, 0);
    __syncthreads();
    for (int t = 0; t < EMB / BK; ++t) {
        const int cur = t & 1;
        if (t + 1 < EMB / BK) GSTAGE(cur ^ 1, (t + 1) * BK);
        const char* Ab = smem[cur];
        const char* Bb = smem[cur] + 16384;
        __builtin_amdgcn_s_setprio(1);
#pragma unroll
        for (int kk = 0; kk < 2; ++kk) {
            bf16x8 af[4], bg[2];
#pragma unroll
            for (int mi = 0; mi < 4; ++mi) {
                const int row = wm * 64 + mi * 16 + lr;
                af[mi] = *(const bf16x8*)(Ab + row * 128 + ((kk * 64 + lg * 16) ^ ((row & 7) << 4)));
            }
#pragma unroll
            for (int ni = 0; ni < 2; ++ni) {
                const int row = wn * 32 + ni * 16 + lr;
                bg[ni] = *(const bf16x8*)(Bb + row * 128 + ((kk * 64 + lg * 16) ^ ((row & 7) << 4)));
            }
#pragma unroll
            for (int mi = 0; mi < 4; ++mi)
#pragma unroll
                for (int ni = 0; ni < 2; ++ni)
                    acc[mi][ni] = __builtin_amdgcn_mfma_f32_16x16x32_bf16(af[mi], bg[ni], acc[mi][ni], 0, 0, 0);
        }
        __builtin_amdgcn_s_setprio(0);
        __syncthreads();
    }
#undef GSTAGE

    const int mat = n0 / EMB;
    if (mat != 2) {
#pragma unroll
        for (int ni = 0; ni < 2; ++ni) {
            int col = n0 + wn * 32 + ni * 16 + lr;
            float bv = bias[col];
            int rem = col - mat * EMB;
            int h = rem >> 6, d = rem & 63;
#pragma unroll
            for (int mi = 0; mi < 4; ++mi) {
#pragma unroll
                for (int j = 0; j < 4; ++j) {
                    int row = m0 + wm * 64 + mi * 16 + lg * 4 + j;
                    int b = row >> 11, n = row & 2047;
                    float v = acc[mi][ni][j] + bv;
                    size_t bh = (size_t)(b * NUM_HEADS + h);
                    if (mat == 0) Qb[(bh * SEQ + n) * HEAD_DIM + d] = f2bf(v * (0.125f * L2E));
                    else          Kb[(bh * SEQ + n) * HEAD_DIM + d] = f2bf(v);
                }
            }
        }
    } else {
        // V: transpose tile through LDS -> coalesced bf16x8 stores into V^T [B,H,D,N]
        short (*Tt)[136] = (short (*)[136])&smem[0][0];   // 34816 B < 65536
#pragma unroll
        for (int ni = 0; ni < 2; ++ni) {
            int col = n0 + wn * 32 + ni * 16 + lr;
            float bv = bias[col];
            int c_loc = wn * 32 + ni * 16 + lr;
#pragma unroll
            for (int mi = 0; mi < 4; ++mi) {
                bf16x4 o4;
#pragma unroll
                for (int j = 0; j < 4; ++j)
                    o4[j] = f2bf(acc[mi][ni][j] + bv);
                *(bf16x4*)&Tt[c_loc][wm * 64 + mi * 16 + lg * 4] = o4;
            }
        }
        __syncthreads();
        const int b = m0 >> 11, nbase = m0 & 2047;
        const int d_loc = tid >> 2;                 // 0..127
        const int nn = (tid & 3) * 32;
        const int rem = n0 - 2 * EMB + d_loc;
        const int h = rem >> 6, d = rem & 63;
        short* dst = Vt + ((size_t)(b * NUM_HEADS + h) * HEAD_DIM + d) * SEQ + nbase + nn;
#pragma unroll
        for (int e = 0; e < 4; ++e)
            *(bf16x8*)&dst[e * 8] = *(const bf16x8*)&Tt[d_loc][nn + e * 8];
    }
}

// ---------- flash attention (round-8 version, verbatim): counted-vmcnt pipeline,
// strict distance-2, PERMUTED K layout -> lane-local P fragments, max-free softmax,
// lsum on the matrix pipe via ones-MFMA. 48KB LDS -> 3 blocks/CU.
__global__ __launch_bounds__(256, 3) void attn_kernel(
    const short* __restrict__ Qb, const short* __restrict__ Kb,
    const short* __restrict__ Vg, short* __restrict__ AO)
{
    __shared__ alignas(16) char Kl[3][8192];   // [64 rows][128 B], permuted keys, swizzled
    __shared__ alignas(16) char Vl[3][8192];   // [64 d][128 B], swizzled

    // bijective XCD swizzle: 768 wgs = 8 XCDs x 96 -> 6 heads per XCD (3 MB K+V in 4 MB L2)
    const int orig = blockIdx.x;
    const int wgid = (orig & 7) * 96 + (orig >> 3);
    const int bh = wgid >> 4;
    const int qb = wgid & 15;
    const int tid = threadIdx.x, lane = tid & 63, wid = tid >> 6;
    const int lr = lane & 15, lg = lane >> 4;
    const int q0 = qb * 128 + wid * 32;
    const short* Qh = Qb + (size_t)bh * SEQ * HEAD_DIM;
    const char*  Khc = (const char*)(Kb + (size_t)bh * SEQ * HEAD_DIM);
    const char*  Vhc = (const char*)(Vg + (size_t)bh * HEAD_DIM * SEQ);

    const int s_r0 = wid * 16 + (lane >> 3);          // LDS row for stage inst 0
    const int s_cb0 = ((lane & 7) * 16) ^ ((s_r0 & 7) << 4);
    const int s_r1 = s_r0 + 8;                        // LDS row for stage inst 1
    const int s_cb1 = ((lane & 7) * 16) ^ ((s_r1 & 7) << 4);
    // permuted K source rows: key = pi(lds_row)
    const int p_r0 = ((s_r0 >> 4) & 1) * 32 + ((s_r0 >> 2) & 3) * 8 + ((s_r0 >> 5) & 1) * 4 + (s_r0 & 3);
    const int p_r1 = ((s_r1 >> 4) & 1) * 32 + ((s_r1 >> 2) & 3) * 8 + ((s_r1 >> 5) & 1) * 4 + (s_r1 & 3);

#define STAGE(kp, vp, kbase)                                                            \
    do {                                                                                \
        __builtin_amdgcn_global_load_lds(                                               \
            (gas_void*)(Khc + ((size_t)(kbase) + p_r0) * 128 + s_cb0),                  \
            (las_void*)((kp) + wid * 2048), 16, 0, 0);                                  \
        __builtin_amdgcn_global_load_lds(                                               \
            (gas_void*)(Khc + ((size_t)(kbase) + p_r1) * 128 + s_cb1),                  \
            (las_void*)((kp) + wid * 2048 + 1024), 16, 0, 0);                           \
        __builtin_amdgcn_global_load_lds(                                               \
            (gas_void*)(Vhc + (size_t)s_r0 * (SEQ * 2) + (size_t)(kbase) * 2 + s_cb0),  \
            (las_void*)((vp) + wid * 2048), 16, 0, 0);                                  \
        __builtin_amdgcn_global_load_lds(                                               \
            (gas_void*)(Vhc + (size_t)s_r1 * (SEQ * 2) + (size_t)(kbase) * 2 + s_cb1),  \
            (las_void*)((vp) + wid * 2048 + 1024), 16, 0, 0);                           \
    } while (0)

    bf16x8 qf[2][2];
#pragma unroll
    for (int c2 = 0; c2 < 2; ++c2)
#pragma unroll
        for (int kk = 0; kk < 2; ++kk)
            qf[c2][kk] = *(const bf16x8*)&Qh[(size_t)(q0 + c2 * 16 + lr) * HEAD_DIM + kk * 32 + lg * 8];

    bf16x8 ones;
#pragma unroll
    for (int e = 0; e < 8; ++e) ones[e] = (short)0x3F80;   // bf16 1.0

    f32x4 acc[2][4] = {};     // acc[c2][f][j] = O^T[d=f*16+lg*4+j][q=lr (chunk c2)]
    f32x4 accl[2] = {};       // lsum[q=lr] via ones-row MFMA

    char *k0p = &Kl[0][0], *k1p = &Kl[1][0], *k2p = &Kl[2][0];
    char *v0p = &Vl[0][0], *v1p = &Vl[1][0], *v2p = &Vl[2][0];

    // prologue: stage tiles 0,1; own tile-0 loads complete BEFORE the first barrier
    STAGE(k0p, v0p, 0);
    STAGE(k1p, v1p, 64);
    asm volatile("s_waitcnt vmcnt(4)" ::: "memory");

    for (int t = 0; t < SEQ / 64; ++t) {
        __builtin_amdgcn_s_barrier();             // all waves done reading tile t-1; tile t landed
        const int tn = (t + 2 < SEQ / 64 ? t + 2 : SEQ / 64 - 1) * 64;
        STAGE(k2p, v2p, tn);                      // overwrites tile t-1 slots (post-barrier)
        asm volatile("s_waitcnt vmcnt(4)" ::: "memory");   // own tiles <= t+1 landed

        // QK(t): S^T = K . Q^T for both q-chunks, sharing each K fragment read
        f32x4 s_[2][4] = {};
        __builtin_amdgcn_s_setprio(1);
#pragma unroll
        for (int c = 0; c < 4; ++c) {
            const int row = c * 16 + lr;
            const int sw = (row & 7) << 4;
            bf16x8 kf0 = *(const bf16x8*)(k0p + row * 128 + ((lg * 16) ^ sw));
            bf16x8 kf1 = *(const bf16x8*)(k0p + row * 128 + ((64 + lg * 16) ^ sw));
            s_[0][c] = __builtin_amdgcn_mfma_f32_16x16x32_bf16(kf0, qf[0][0], s_[0][c], 0, 0, 0);
            s_[0][c] = __builtin_amdgcn_mfma_f32_16x16x32_bf16(kf1, qf[0][1], s_[0][c], 0, 0, 0);
            s_[1][c] = __builtin_amdgcn_mfma_f32_16x16x32_bf16(kf0, qf[1][0], s_[1][c], 0, 0, 0);
            s_[1][c] = __builtin_amdgcn_mfma_f32_16x16x32_bf16(kf1, qf[1][1], s_[1][c], 0, 0, 0);
        }
        __builtin_amdgcn_s_setprio(0);

        // SM(t): max-free exp2 + lane-local pack (permuted K makes P fragments lane-local)
        bf16x8 pb[2][2];
#pragma unroll
        for (int c2 = 0; c2 < 2; ++c2) {
            u32x4 w0, w1;
            w0[0] = pk2(__builtin_amdgcn_exp2f(s_[c2][0][0]), __builtin_amdgcn_exp2f(s_[c2][0][1]));
            w0[1] = pk2(__builtin_amdgcn_exp2f(s_[c2][0][2]), __builtin_amdgcn_exp2f(s_[c2][0][3]));
            w0[2] = pk2(__builtin_amdgcn_exp2f(s_[c2][2][0]), __builtin_amdgcn_exp2f(s_[c2][2][1]));
            w0[3] = pk2(__builtin_amdgcn_exp2f(s_[c2][2][2]), __builtin_amdgcn_exp2f(s_[c2][2][3]));
            w1[0] = pk2(__builtin_amdgcn_exp2f(s_[c2][1][0]), __builtin_amdgcn_exp2f(s_[c2][1][1]));
            w1[1] = pk2(__builtin_amdgcn_exp2f(s_[c2][1][2]), __builtin_amdgcn_exp2f(s_[c2][1][3]));
            w1[2] = pk2(__builtin_amdgcn_exp2f(s_[c2][3][0]), __builtin_amdgcn_exp2f(s_[c2][3][1]));
            w1[3] = pk2(__builtin_amdgcn_exp2f(s_[c2][3][2]), __builtin_amdgcn_exp2f(s_[c2][3][3]));
            pb[c2][0] = __builtin_bit_cast(bf16x8, w0);
            pb[c2][1] = __builtin_bit_cast(bf16x8, w1);
        }

        // PV(t): O^T += V^T . P^T; lsum += ones . P^T (matrix pipe does the row-sum)
        __builtin_amdgcn_s_setprio(1);
#pragma unroll
        for (int f = 0; f < 4; ++f) {
            const int row = f * 16 + lr;
            const int sw = (row & 7) << 4;
            bf16x8 vf0 = *(const bf16x8*)(v0p + row * 128 + ((lg * 16) ^ sw));
            bf16x8 vf1 = *(const bf16x8*)(v0p + row * 128 + ((64 + lg * 16) ^ sw));
            acc[0][f] = __builtin_amdgcn_mfma_f32_16x16x32_bf16(vf0, pb[0][0], acc[0][f], 0, 0, 0);
            acc[0][f] = __builtin_amdgcn_mfma_f32_16x16x32_bf16(vf1, pb[0][1], acc[0][f], 0, 0, 0);
            acc[1][f] = __builtin_amdgcn_mfma_f32_16x16x32_bf16(vf0, pb[1][0], acc[1][f], 0, 0, 0);
            acc[1][f] = __builtin_amdgcn_mfma_f32_16x16x32_bf16(vf1, pb[1][1], acc[1][f], 0, 0, 0);
        }
        accl[0] = __builtin_amdgcn_mfma_f32_16x16x32_bf16(ones, pb[0][0], accl[0], 0, 0, 0);
        accl[0] = __builtin_amdgcn_mfma_f32_16x16x32_bf16(ones, pb[0][1], accl[0], 0, 0, 0);
        accl[1] = __builtin_amdgcn_mfma_f32_16x16x32_bf16(ones, pb[1][0], accl[1], 0, 0, 0);
        accl[1] = __builtin_amdgcn_mfma_f32_16x16x32_bf16(ones, pb[1][1], accl[1], 0, 0, 0);
        __builtin_amdgcn_s_setprio(0);

        // rotate buffers: read slot <- next, next <- staged, staged <- retired
        char* kt_ = k0p; k0p = k1p; k1p = k2p; k2p = kt_;
        char* vt_ = v0p; v0p = v1p; v1p = v2p; v2p = vt_;
    }
#undef STAGE

    // epilogue: every lane holds lsum for its q (= lr) in accl
    const int b = bh / NUM_HEADS, h = bh - b * NUM_HEADS;
#pragma unroll
    for (int c2 = 0; c2 < 2; ++c2) {
        const float inv = 1.f / accl[c2][0];
        const size_t rowbase = ((size_t)(b * SEQ + q0 + c2 * 16 + lr)) * EMB + h * HEAD_DIM;
#pragma unroll
        for (int f = 0; f < 4; ++f) {
            bf16x4 o4;
#pragma unroll
            for (int j = 0; j < 4; ++j)
                o4[j] = f2bf(acc[c2][f][j] * inv);
            *(bf16x4*)&AO[rowbase + f * 16 + lg * 4] = o4;
        }
    }
}

// ---------- proj GEMM: AO[16384][384] bf16 @ WT[384][384] bf16 + bias -> f32 out
__global__ __launch_bounds__(256, 3) void proj_gemm_kernel(
    const short* __restrict__ Ain, const short* __restrict__ WT,
    const float* __restrict__ bias, float* __restrict__ Out)
{
    __shared__ alignas(16) char smem[2][24576];   // [buf][A 8K | B 16K]
    const int orig = blockIdx.x;
    const int idx = orig >> 3;
    const int m0 = ((orig & 7) * 32 + idx / 3) * 64;
    const int n0 = (idx % 3) * 128;
    const int tid = threadIdx.x;
    const int lane = tid & 63, wid = tid >> 6;
    const int wm = wid >> 1, wn = wid & 1;
    const int lr = lane & 15, lg = lane >> 4;
    const char* Ac = (const char*)Ain;
    const char* Wc = (const char*)WT;

    const int a_r = wid * 16 + (lane >> 3);
    const int b_r = wid * 32 + (lane >> 3);
    const int t_cb = ((lane & 7) * 16) ^ (((lane >> 3) & 7) << 4);

#define PSTAGE(buf, k0)                                                                     \
    do {                                                                                    \
        _Pragma("unroll") for (int i = 0; i < 2; ++i)                                       \
            __builtin_amdgcn_global_load_lds(                                               \
                (gas_void*)(Ac + ((size_t)(m0 + a_r + i * 8)) * (EMB * 2) + (k0) * 2 + t_cb), \
                (las_void*)(&smem[buf][wid * 2048 + i * 1024]), 16, 0, 0);                  \
        _Pragma("unroll") for (int i = 0; i < 4; ++i)                                       \
            __builtin_amdgcn_global_load_lds(                                               \
                (gas_void*)(Wc + ((size_t)(n0 + b_r + i * 8)) * (EMB * 2) + (k0) * 2 + t_cb), \
                (las_void*)(&smem[buf][8192 + wid * 4096 + i * 1024]), 16, 0, 0);           \
    } while (0)

    f32x4 acc[2][4] = {};

    PSTAGE(0, 0);
    __syncthreads();
    for (int t = 0; t < EMB / BK; ++t) {
        const int cur = t & 1;
        if (t + 1 < EMB / BK) PSTAGE(cur ^ 1, (t + 1) * BK);
        const char* Ab = smem[cur];
        const char* Bb = smem[cur] + 8192;
        __builtin_amdgcn_s_setprio(1);
#pragma unroll
        for (int kk = 0; kk < 2; ++kk) {
            bf16x8 af[2], bg[4];
#pragma unroll
            for (int mi = 0; mi < 2; ++mi) {
                const int row = wm * 32 + mi * 16 + lr;
                af[mi] = *(const bf16x8*)(Ab + row * 128 + ((kk * 64 + lg * 16) ^ ((row & 7) << 4)));
            }
#pragma unroll
            for (int ni = 0; ni < 4; ++ni) {
                const int row = wn * 64 + ni * 16 + lr;
                bg[ni] = *(const bf16x8*)(Bb + row * 128 + ((kk * 64 + lg * 16) ^ ((row & 7) << 4)));
            }
#pragma unroll
            for (int mi = 0; mi < 2; ++mi)
#pragma unroll
                for (int ni = 0; ni < 4; ++ni)
                    acc[mi][ni] = __builtin_amdgcn_mfma_f32_16x16x32_bf16(af[mi], bg[ni], acc[mi][ni], 0, 0, 0);
        }
        __builtin_amdgcn_s_setprio(0);
        __syncthreads();
    }
#undef PSTAGE

#pragma unroll
    for (int ni = 0; ni < 4; ++ni) {
        int col = n0 + wn * 64 + ni * 16 + lr;
        float bv = bias[col];
#pragma unroll
        for (int mi = 0; mi < 2; ++mi)
#pragma unroll
            for (int j = 0; j < 4; ++j) {
                int row = m0 + wm * 32 + mi * 16 + lg * 4 + j;
                Out[(size_t)row * EMB + col] = acc[mi][ni][j] + bv;
            }
    }
}

extern "C" void kernel_launch(void* const* d_in, const int* in_sizes, int n_in,
                              void* d_out, int out_size, void* d_ws, size_t ws_size,
                              hipStream_t stream) {
    const float* x      = (const float*)d_in[0];
    const float* qkv_w  = (const float*)d_in[1];   // [384][1152]
    const float* qkv_b  = (const float*)d_in[2];   // [1152]
    const float* proj_w = (const float*)d_in[3];   // [384][384]
    const float* proj_b = (const float*)d_in[4];   // [384]
    float* out = (float*)d_out;

    // workspace layout (bytes); Xb shares the AO slot (Xb consumed before AO written)
    char* ws = (char*)d_ws;
    short* qkv_wT  = (short*)(ws);               // [1152][384] bf16
    short* proj_wT = (short*)(ws + 884736);      // [384][384]  bf16
    short* Qb      = (short*)(ws + 1179648);     // [B,H,N,D]   bf16 (pre-scaled 0.125*log2e)
    short* Kb      = (short*)(ws + 13762560);    // [B,H,N,D]   bf16
    short* Vt      = (short*)(ws + 26345472);    // [B,H,D,N]   bf16
    short* AOXb    = (short*)(ws + 38928384);    // [B,N,C] bf16: Xb then AO

    prep_kernel<<<dim3(3648), 256, 0, stream>>>(x, qkv_w, proj_w, AOXb, qkv_wT, proj_wT);
    qkv_gemm_kernel<<<dim3(ROWS / BM * (QKV_COLS / BN)), 512, 0, stream>>>(AOXb, qkv_wT, qkv_b, Qb, Kb, Vt);
    attn_kernel<<<dim3(NBH * (SEQ / 128)), 256, 0, stream>>>(Qb, Kb, Vt, AOXb);
    proj_gemm_kernel<<<dim3(ROWS / 64 * (EMB / 128)), 256, 0, stream>>>(AOXb, proj_wT, proj_b, out);
}

// Round 13
// 112.072 us; speedup vs baseline: 1.4491x; 1.0381x over previous
//
#include <hip/hip_runtime.h>
#include <hip/hip_bf16.h>
#include <stdint.h>

#define NUM_HEADS 6
#define HEAD_DIM  64
#define EMB       384
#define SEQ       2048
#define NBATCH    8
#define NBH       48        // B*H
#define QKV_COLS  1152
#define ROWS      16384     // B*SEQ
#define L2E       1.44269504f

typedef __attribute__((ext_vector_type(8))) short bf16x8;
typedef __attribute__((ext_vector_type(4))) short bf16x4;
typedef __attribute__((ext_vector_type(4))) float f32x4;
typedef __attribute__((ext_vector_type(4))) unsigned int u32x4;

typedef const __attribute__((address_space(1))) void gas_void;
typedef __attribute__((address_space(3))) void las_void;

static __device__ __forceinline__ short f2bf(float f) {
    __hip_bfloat16 h = __float2bfloat16(f);     // HW RNE
    return __builtin_bit_cast(short, h);
}
static __device__ __forceinline__ uint32_t pk2(float lo, float hi) {
    return (uint32_t)(uint16_t)f2bf(lo) | ((uint32_t)(uint16_t)f2bf(hi) << 16);
}

// ---------- fused prep: xcvt (blocks 0..3071) + wtrans qkv_w (3072..3503) + wtrans proj_w (3504..3647)
__global__ void prep_kernel(const float* __restrict__ x,
                            const float* __restrict__ qkv_w, const float* __restrict__ proj_w,
                            short* __restrict__ Xb, short* __restrict__ qkv_wT, short* __restrict__ proj_wT)
{
    __shared__ float tile[32][33];
    const int id = blockIdx.x, tid = threadIdx.x;
    if (id < 3072) {                       // X f32 -> bf16, 8 elems/thread
        int i = (id * 256 + tid) * 8;
        f32x4 a = *(const f32x4*)&x[i];
        f32x4 b = *(const f32x4*)&x[i + 4];
        bf16x8 o;
        o[0] = f2bf(a[0]); o[1] = f2bf(a[1]); o[2] = f2bf(a[2]); o[3] = f2bf(a[3]);
        o[4] = f2bf(b[0]); o[5] = f2bf(b[1]); o[6] = f2bf(b[2]); o[7] = f2bf(b[3]);
        *(bf16x8*)&Xb[i] = o;
        return;
    }
    const float* in; short* outp; int cols, bx, by;
    if (id < 3504) { in = qkv_w; outp = qkv_wT; cols = QKV_COLS; bx = (id - 3072) % 36; by = (id - 3072) / 36; }
    else           { in = proj_w; outp = proj_wT; cols = EMB;    bx = (id - 3504) % 12; by = (id - 3504) / 12; }
    const int c0 = bx * 32, r0 = by * 32;
    const int xx = tid & 31, yy = tid >> 5;     // 32 x 8
#pragma unroll
    for (int i = 0; i < 32; i += 8)
        tile[yy + i][xx] = in[(size_t)(r0 + yy + i) * cols + c0 + xx];
    __syncthreads();
#pragma unroll
    for (int i = 0; i < 32; i += 8)
        outp[(size_t)(c0 + yy + i) * EMB + r0 + xx] = f2bf(tile[xx][yy + i]);
}

#define BM 128
#define BN 128
#define BK 64

// ---------- QKV GEMM: Xb[16384][384] bf16 @ WT[1152][384] bf16 -> Q(x0.125*log2e),K [B,H,N,D], V^T [B,H,D,N]
__global__ __launch_bounds__(256, 2) void qkv_gemm_kernel(
    const short* __restrict__ Xb, const short* __restrict__ WT,
    const float* __restrict__ bias,
    short* __restrict__ Qb, short* __restrict__ Kb, short* __restrict__ Vt)
{
    __shared__ alignas(16) char smem[2][32768];   // [buf][A 16K | B 16K]; reused as Tt in epilogue
    const int orig = blockIdx.x;
    const int wgid = (orig & 7) * 144 + (orig >> 3);   // XCD-chunked
    const int m0 = (wgid / 9) * BM;
    const int n0 = (wgid % 9) * BN;
    const int tid = threadIdx.x;
    const int lane = tid & 63, wid = tid >> 6;
    const int wm = wid >> 1, wn = wid & 1;
    const int lr = lane & 15, lg = lane >> 4;
    const char* Xc = (const char*)Xb;
    const char* Wc = (const char*)WT;

    const int t_r = wid * 32 + (lane >> 3);
    const int t_cb = ((lane & 7) * 16) ^ (((lane >> 3) & 7) << 4);

#define GSTAGE(buf, k0)                                                                     \
    do {                                                                                    \
        _Pragma("unroll") for (int i = 0; i < 4; ++i)                                       \
            __builtin_amdgcn_global_load_lds(                                               \
                (gas_void*)(Xc + ((size_t)(m0 + t_r + i * 8)) * (EMB * 2) + (k0) * 2 + t_cb), \
                (las_void*)(&smem[buf][wid * 4096 + i * 1024]), 16, 0, 0);                  \
        _Pragma("unroll") for (int i = 0; i < 4; ++i)                                       \
            __builtin_amdgcn_global_load_lds(                                               \
                (gas_void*)(Wc + ((size_t)(n0 + t_r + i * 8)) * (EMB * 2) + (k0) * 2 + t_cb), \
                (las_void*)(&smem[buf][16384 + wid * 4096 + i * 1024]), 16, 0, 0);          \
    } while (0)

    f32x4 acc[4][4] = {};

    GSTAGE(0, 0);
    __syncthreads();
    for (int t = 0; t < EMB / BK; ++t) {
        const int cur = t & 1;
        if (t + 1 < EMB / BK) GSTAGE(cur ^ 1, (t + 1) * BK);
        const char* Ab = smem[cur];
        const char* Bb = smem[cur] + 16384;
        __builtin_amdgcn_s_setprio(1);
#pragma unroll
        for (int kk = 0; kk < 2; ++kk) {
            bf16x8 af[4], bg[4];
#pragma unroll
            for (int mi = 0; mi < 4; ++mi) {
                const int row = wm * 64 + mi * 16 + lr;
                af[mi] = *(const bf16x8*)(Ab + row * 128 + ((kk * 64 + lg * 16) ^ ((row & 7) << 4)));
            }
#pragma unroll
            for (int ni = 0; ni < 4; ++ni) {
                const int row = wn * 64 + ni * 16 + lr;
                bg[ni] = *(const bf16x8*)(Bb + row * 128 + ((kk * 64 + lg * 16) ^ ((row & 7) << 4)));
            }
#pragma unroll
            for (int mi = 0; mi < 4; ++mi)
#pragma unroll
                for (int ni = 0; ni < 4; ++ni)
                    acc[mi][ni] = __builtin_amdgcn_mfma_f32_16x16x32_bf16(af[mi], bg[ni], acc[mi][ni], 0, 0, 0);
        }
        __builtin_amdgcn_s_setprio(0);
        __syncthreads();
    }
#undef GSTAGE

    const int mat = n0 / EMB;
    if (mat != 2) {
#pragma unroll
        for (int ni = 0; ni < 4; ++ni) {
            int col = n0 + wn * 64 + ni * 16 + lr;
            float bv = bias[col];
            int rem = col - mat * EMB;
            int h = rem >> 6, d = rem & 63;
#pragma unroll
            for (int mi = 0; mi < 4; ++mi) {
#pragma unroll
                for (int j = 0; j < 4; ++j) {
                    int row = m0 + wm * 64 + mi * 16 + lg * 4 + j;
                    int b = row >> 11, n = row & 2047;
                    float v = acc[mi][ni][j] + bv;
                    size_t bh = (size_t)(b * NUM_HEADS + h);
                    if (mat == 0) Qb[(bh * SEQ + n) * HEAD_DIM + d] = f2bf(v * (0.125f * L2E));
                    else          Kb[(bh * SEQ + n) * HEAD_DIM + d] = f2bf(v);
                }
            }
        }
    } else {
        // V: transpose tile through LDS -> coalesced bf16x8 stores into V^T [B,H,D,N]
        short (*Tt)[136] = (short (*)[136])&smem[0][0];
#pragma unroll
        for (int ni = 0; ni < 4; ++ni) {
            int col = n0 + wn * 64 + ni * 16 + lr;
            float bv = bias[col];
            int c_loc = wn * 64 + ni * 16 + lr;
#pragma unroll
            for (int mi = 0; mi < 4; ++mi) {
                bf16x4 o4;
#pragma unroll
                for (int j = 0; j < 4; ++j)
                    o4[j] = f2bf(acc[mi][ni][j] + bv);
                *(bf16x4*)&Tt[c_loc][wm * 64 + mi * 16 + lg * 4] = o4;
            }
        }
        __syncthreads();
        const int b = m0 >> 11, nbase = m0 & 2047;
        const int d_loc = tid >> 1;
        const int nn = (tid & 1) * 64;
        const int rem = n0 - 2 * EMB + d_loc;
        const int h = rem >> 6, d = rem & 63;
        short* dst = Vt + ((size_t)(b * NUM_HEADS + h) * HEAD_DIM + d) * SEQ + nbase + nn;
#pragma unroll
        for (int e = 0; e < 8; ++e)
            *(bf16x8*)&dst[e * 8] = *(const bf16x8*)&Tt[d_loc][nn + e * 8];
    }
}

// ---------- flash attention: counted-vmcnt pipeline, strict distance-2, PERMUTED K layout
// -> lane-local P fragments, max-free softmax, lsum via ones-MFMA. 48KB LDS -> 3 blocks/CU.
__global__ __launch_bounds__(256, 3) void attn_kernel(
    const short* __restrict__ Qb, const short* __restrict__ Kb,
    const short* __restrict__ Vg, short* __restrict__ AO)
{
    __shared__ alignas(16) char Kl[3][8192];   // [64 rows][128 B], permuted keys, swizzled
    __shared__ alignas(16) char Vl[3][8192];   // [64 d][128 B], swizzled

    // bijective XCD swizzle: 768 wgs = 8 XCDs x 96 -> 6 heads per XCD (3 MB K+V in 4 MB L2)
    const int orig = blockIdx.x;
    const int wgid = (orig & 7) * 96 + (orig >> 3);
    const int bh = wgid >> 4;
    const int qb = wgid & 15;
    const int tid = threadIdx.x, lane = tid & 63, wid = tid >> 6;
    const int lr = lane & 15, lg = lane >> 4;
    const int q0 = qb * 128 + wid * 32;
    const short* Qh = Qb + (size_t)bh * SEQ * HEAD_DIM;
    const char*  Khc = (const char*)(Kb + (size_t)bh * SEQ * HEAD_DIM);
    const char*  Vhc = (const char*)(Vg + (size_t)bh * HEAD_DIM * SEQ);

    const int s_r0 = wid * 16 + (lane >> 3);          // LDS row for stage inst 0
    const int s_cb0 = ((lane & 7) * 16) ^ ((s_r0 & 7) << 4);
    const int s_r1 = s_r0 + 8;                        // LDS row for stage inst 1
    const int s_cb1 = ((lane & 7) * 16) ^ ((s_r1 & 7) << 4);
    // permuted K source rows: key = pi(lds_row)
    const int p_r0 = ((s_r0 >> 4) & 1) * 32 + ((s_r0 >> 2) & 3) * 8 + ((s_r0 >> 5) & 1) * 4 + (s_r0 & 3);
    const int p_r1 = ((s_r1 >> 4) & 1) * 32 + ((s_r1 >> 2) & 3) * 8 + ((s_r1 >> 5) & 1) * 4 + (s_r1 & 3);

#define STAGE(kp, vp, kbase)                                                            \
    do {                                                                                \
        __builtin_amdgcn_global_load_lds(                                               \
            (gas_void*)(Khc + ((size_t)(kbase) + p_r0) * 128 + s_cb0),                  \
            (las_void*)((kp) + wid * 2048), 16, 0, 0);                                  \
        __builtin_amdgcn_global_load_lds(                                               \
            (gas_void*)(Khc + ((size_t)(kbase) + p_r1) * 128 + s_cb1),                  \
            (las_void*)((kp) + wid * 2048 + 1024), 16, 0, 0);                           \
        __builtin_amdgcn_global_load_lds(                                               \
            (gas_void*)(Vhc + (size_t)s_r0 * (SEQ * 2) + (size_t)(kbase) * 2 + s_cb0),  \
            (las_void*)((vp) + wid * 2048), 16, 0, 0);                                  \
        __builtin_amdgcn_global_load_lds(                                               \
            (gas_void*)(Vhc + (size_t)s_r1 * (SEQ * 2) + (size_t)(kbase) * 2 + s_cb1),  \
            (las_void*)((vp) + wid * 2048 + 1024), 16, 0, 0);                           \
    } while (0)

    bf16x8 qf[2][2];
#pragma unroll
    for (int c2 = 0; c2 < 2; ++c2)
#pragma unroll
        for (int kk = 0; kk < 2; ++kk)
            qf[c2][kk] = *(const bf16x8*)&Qh[(size_t)(q0 + c2 * 16 + lr) * HEAD_DIM + kk * 32 + lg * 8];

    bf16x8 ones;
#pragma unroll
    for (int e = 0; e < 8; ++e) ones[e] = (short)0x3F80;   // bf16 1.0

    f32x4 acc[2][4] = {};     // acc[c2][f][j] = O^T[d=f*16+lg*4+j][q=lr (chunk c2)]
    f32x4 accl[2] = {};       // lsum[q=lr] via ones-row MFMA

    char *k0p = &Kl[0][0], *k1p = &Kl[1][0], *k2p = &Kl[2][0];
    char *v0p = &Vl[0][0], *v1p = &Vl[1][0], *v2p = &Vl[2][0];

    // prologue: stage tiles 0,1; own tile-0 loads complete BEFORE the first barrier
    STAGE(k0p, v0p, 0);
    STAGE(k1p, v1p, 64);
    asm volatile("s_waitcnt vmcnt(4)" ::: "memory");

    for (int t = 0; t < SEQ / 64; ++t) {
        __builtin_amdgcn_s_barrier();             // all waves done reading tile t-1; tile t landed
        const int tn = (t + 2 < SEQ / 64 ? t + 2 : SEQ / 64 - 1) * 64;
        STAGE(k2p, v2p, tn);                      // overwrites tile t-1 slots (post-barrier)
        asm volatile("s_waitcnt vmcnt(4)" ::: "memory");   // own tiles <= t+1 landed

        // QK(t): S^T = K . Q^T for both q-chunks, sharing each K fragment read
        f32x4 s_[2][4] = {};
        __builtin_amdgcn_s_setprio(1);
#pragma unroll
        for (int c = 0; c < 4; ++c) {
            const int row = c * 16 + lr;
            const int sw = (row & 7) << 4;
            bf16x8 kf0 = *(const bf16x8*)(k0p + row * 128 + ((lg * 16) ^ sw));
            bf16x8 kf1 = *(const bf16x8*)(k0p + row * 128 + ((64 + lg * 16) ^ sw));
            s_[0][c] = __builtin_amdgcn_mfma_f32_16x16x32_bf16(kf0, qf[0][0], s_[0][c], 0, 0, 0);
            s_[0][c] = __builtin_amdgcn_mfma_f32_16x16x32_bf16(kf1, qf[0][1], s_[0][c], 0, 0, 0);
            s_[1][c] = __builtin_amdgcn_mfma_f32_16x16x32_bf16(kf0, qf[1][0], s_[1][c], 0, 0, 0);
            s_[1][c] = __builtin_amdgcn_mfma_f32_16x16x32_bf16(kf1, qf[1][1], s_[1][c], 0, 0, 0);
        }
        __builtin_amdgcn_s_setprio(0);

        // SM(t): max-free exp2 + lane-local pack (permuted K makes P fragments lane-local)
        bf16x8 pb[2][2];
#pragma unroll
        for (int c2 = 0; c2 < 2; ++c2) {
            u32x4 w0, w1;
            w0[0] = pk2(__builtin_amdgcn_exp2f(s_[c2][0][0]), __builtin_amdgcn_exp2f(s_[c2][0][1]));
            w0[1] = pk2(__builtin_amdgcn_exp2f(s_[c2][0][2]), __builtin_amdgcn_exp2f(s_[c2][0][3]));
            w0[2] = pk2(__builtin_amdgcn_exp2f(s_[c2][2][0]), __builtin_amdgcn_exp2f(s_[c2][2][1]));
            w0[3] = pk2(__builtin_amdgcn_exp2f(s_[c2][2][2]), __builtin_amdgcn_exp2f(s_[c2][2][3]));
            w1[0] = pk2(__builtin_amdgcn_exp2f(s_[c2][1][0]), __builtin_amdgcn_exp2f(s_[c2][1][1]));
            w1[1] = pk2(__builtin_amdgcn_exp2f(s_[c2][1][2]), __builtin_amdgcn_exp2f(s_[c2][1][3]));
            w1[2] = pk2(__builtin_amdgcn_exp2f(s_[c2][3][0]), __builtin_amdgcn_exp2f(s_[c2][3][1]));
            w1[3] = pk2(__builtin_amdgcn_exp2f(s_[c2][3][2]), __builtin_amdgcn_exp2f(s_[c2][3][3]));
            pb[c2][0] = __builtin_bit_cast(bf16x8, w0);
            pb[c2][1] = __builtin_bit_cast(bf16x8, w1);
        }

        // PV(t): O^T += V^T . P^T; lsum += ones . P^T (matrix pipe does the row-sum)
        __builtin_amdgcn_s_setprio(1);
#pragma unroll
        for (int f = 0; f < 4; ++f) {
            const int row = f * 16 + lr;
            const int sw = (row & 7) << 4;
            bf16x8 vf0 = *(const bf16x8*)(v0p + row * 128 + ((lg * 16) ^ sw));
            bf16x8 vf1 = *(const bf16x8*)(v0p + row * 128 + ((64 + lg * 16) ^ sw));
            acc[0][f] = __builtin_amdgcn_mfma_f32_16x16x32_bf16(vf0, pb[0][0], acc[0][f], 0, 0, 0);
            acc[0][f] = __builtin_amdgcn_mfma_f32_16x16x32_bf16(vf1, pb[0][1], acc[0][f], 0, 0, 0);
            acc[1][f] = __builtin_amdgcn_mfma_f32_16x16x32_bf16(vf0, pb[1][0], acc[1][f], 0, 0, 0);
            acc[1][f] = __builtin_amdgcn_mfma_f32_16x16x32_bf16(vf1, pb[1][1], acc[1][f], 0, 0, 0);
        }
        accl[0] = __builtin_amdgcn_mfma_f32_16x16x32_bf16(ones, pb[0][0], accl[0], 0, 0, 0);
        accl[0] = __builtin_amdgcn_mfma_f32_16x16x32_bf16(ones, pb[0][1], accl[0], 0, 0, 0);
        accl[1] = __builtin_amdgcn_mfma_f32_16x16x32_bf16(ones, pb[1][0], accl[1], 0, 0, 0);
        accl[1] = __builtin_amdgcn_mfma_f32_16x16x32_bf16(ones, pb[1][1], accl[1], 0, 0, 0);
        __builtin_amdgcn_s_setprio(0);

        // rotate buffers: read slot <- next, next <- staged, staged <- retired
        char* kt_ = k0p; k0p = k1p; k1p = k2p; k2p = kt_;
        char* vt_ = v0p; v0p = v1p; v1p = v2p; v2p = vt_;
    }
#undef STAGE

    // epilogue: every lane holds lsum for its q (= lr) in accl
    const int b = bh / NUM_HEADS, h = bh - b * NUM_HEADS;
#pragma unroll
    for (int c2 = 0; c2 < 2; ++c2) {
        const float inv = 1.f / accl[c2][0];
        const size_t rowbase = ((size_t)(b * SEQ + q0 + c2 * 16 + lr)) * EMB + h * HEAD_DIM;
#pragma unroll
        for (int f = 0; f < 4; ++f) {
            bf16x4 o4;
#pragma unroll
            for (int j = 0; j < 4; ++j)
                o4[j] = f2bf(acc[c2][f][j] * inv);
            *(bf16x4*)&AO[rowbase + f * 16 + lg * 4] = o4;
        }
    }
}

// ---------- proj GEMM: AO[16384][384] bf16 @ WT[384][384] bf16 + bias -> f32 out
__global__ __launch_bounds__(256, 3) void proj_gemm_kernel(
    const short* __restrict__ Ain, const short* __restrict__ WT,
    const float* __restrict__ bias, float* __restrict__ Out)
{
    __shared__ alignas(16) char smem[2][24576];   // [buf][A 8K | B 16K]
    const int orig = blockIdx.x;
    const int idx = orig >> 3;
    const int m0 = ((orig & 7) * 32 + idx / 3) * 64;
    const int n0 = (idx % 3) * 128;
    const int tid = threadIdx.x;
    const int lane = tid & 63, wid = tid >> 6;
    const int wm = wid >> 1, wn = wid & 1;
    const int lr = lane & 15, lg = lane >> 4;
    const char* Ac = (const char*)Ain;
    const char* Wc = (const char*)WT;

    const int a_r = wid * 16 + (lane >> 3);
    const int b_r = wid * 32 + (lane >> 3);
    const int t_cb = ((lane & 7) * 16) ^ (((lane >> 3) & 7) << 4);

#define PSTAGE(buf, k0)                                                                     \
    do {                                                                                    \
        _Pragma("unroll") for (int i = 0; i < 2; ++i)                                       \
            __builtin_amdgcn_global_load_lds(                                               \
                (gas_void*)(Ac + ((size_t)(m0 + a_r + i * 8)) * (EMB * 2) + (k0) * 2 + t_cb), \
                (las_void*)(&smem[buf][wid * 2048 + i * 1024]), 16, 0, 0);                  \
        _Pragma("unroll") for (int i = 0; i < 4; ++i)                                       \
            __builtin_amdgcn_global_load_lds(                                               \
                (gas_void*)(Wc + ((size_t)(n0 + b_r + i * 8)) * (EMB * 2) + (k0) * 2 + t_cb), \
                (las_void*)(&smem[buf][8192 + wid * 4096 + i * 1024]), 16, 0, 0);           \
    } while (0)

    f32x4 acc[2][4] = {};

    PSTAGE(0, 0);
    __syncthreads();
    for (int t = 0; t < EMB / BK; ++t) {
        const int cur = t & 1;
        if (t + 1 < EMB / BK) PSTAGE(cur ^ 1, (t + 1) * BK);
        const char* Ab = smem[cur];
        const char* Bb = smem[cur] + 8192;
        __builtin_amdgcn_s_setprio(1);
#pragma unroll
        for (int kk = 0; kk < 2; ++kk) {
            bf16x8 af[2], bg[4];
#pragma unroll
            for (int mi = 0; mi < 2; ++mi) {
                const int row = wm * 32 + mi * 16 + lr;
                af[mi] = *(const bf16x8*)(Ab + row * 128 + ((kk * 64 + lg * 16) ^ ((row & 7) << 4)));
            }
#pragma unroll
            for (int ni = 0; ni < 4; ++ni) {
                const int row = wn * 64 + ni * 16 + lr;
                bg[ni] = *(const bf16x8*)(Bb + row * 128 + ((kk * 64 + lg * 16) ^ ((row & 7) << 4)));
            }
#pragma unroll
            for (int mi = 0; mi < 2; ++mi)
#pragma unroll
                for (int ni = 0; ni < 4; ++ni)
                    acc[mi][ni] = __builtin_amdgcn_mfma_f32_16x16x32_bf16(af[mi], bg[ni], acc[mi][ni], 0, 0, 0);
        }
        __builtin_amdgcn_s_setprio(0);
        __syncthreads();
    }
#undef PSTAGE

#pragma unroll
    for (int ni = 0; ni < 4; ++ni) {
        int col = n0 + wn * 64 + ni * 16 + lr;
        float bv = bias[col];
#pragma unroll
        for (int mi = 0; mi < 2; ++mi)
#pragma unroll
            for (int j = 0; j < 4; ++j) {
                int row = m0 + wm * 32 + mi * 16 + lg * 4 + j;
                Out[(size_t)row * EMB + col] = acc[mi][ni][j] + bv;
            }
    }
}

extern "C" void kernel_launch(void* const* d_in, const int* in_sizes, int n_in,
                              void* d_out, int out_size, void* d_ws, size_t ws_size,
                              hipStream_t stream) {
    const float* x      = (const float*)d_in[0];
    const float* qkv_w  = (const float*)d_in[1];   // [384][1152]
    const float* qkv_b  = (const float*)d_in[2];   // [1152]
    const float* proj_w = (const float*)d_in[3];   // [384][384]
    const float* proj_b = (const float*)d_in[4];   // [384]
    float* out = (float*)d_out;

    // workspace layout (bytes); Xb shares the AO slot (Xb consumed before AO written)
    char* ws = (char*)d_ws;
    short* qkv_wT  = (short*)(ws);               // [1152][384] bf16
    short* proj_wT = (short*)(ws + 884736);      // [384][384]  bf16
    short* Qb      = (short*)(ws + 1179648);     // [B,H,N,D]   bf16 (pre-scaled 0.125*log2e)
    short* Kb      = (short*)(ws + 13762560);    // [B,H,N,D]   bf16
    short* Vt      = (short*)(ws + 26345472);    // [B,H,D,N]   bf16
    short* AOXb    = (short*)(ws + 38928384);    // [B,N,C] bf16: Xb then AO

    prep_kernel<<<dim3(3648), 256, 0, stream>>>(x, qkv_w, proj_w, AOXb, qkv_wT, proj_wT);
    qkv_gemm_kernel<<<dim3(ROWS / BM * (QKV_COLS / BN)), 256, 0, stream>>>(AOXb, qkv_wT, qkv_b, Qb, Kb, Vt);
    attn_kernel<<<dim3(NBH * (SEQ / 128)), 256, 0, stream>>>(Qb, Kb, Vt, AOXb);
    proj_gemm_kernel<<<dim3(ROWS / 64 * (EMB / 128)), 256, 0, stream>>>(AOXb, proj_wT, proj_b, out);
}